// Round 4
// baseline (3472.975 us; speedup 1.0000x reference)
//
#include <hip/hip_runtime.h>
#include <math.h>

#define B_SZ   2
#define LSEQ   2048
#define DM     1024
#define DI     2048
#define NST    16
#define DTR    64
#define XDBL_N 96
#define NTOK   (B_SZ * LSEQ)
#define NCH    32
#define CS     64
#define EPSF   1e-5f
#define STEPF  0.99f
#define FP_ITERS 8
#define NEXT   2176   // DI + 128 (32 Wbc cols + 96 pad)

typedef __attribute__((ext_vector_type(8))) short bf16x8;
typedef __attribute__((ext_vector_type(4))) float f32x4;
typedef unsigned short ushort_t;

__device__ __forceinline__ ushort_t f2bf(float v) {
    unsigned u = __float_as_uint(v);
    unsigned r = (u + 0x7fffu + ((u >> 16) & 1u)) >> 16;   // RNE
    return (ushort_t)r;
}
__device__ __forceinline__ float bf2f(ushort_t h) {
    return __uint_as_float(((unsigned)h) << 16);
}
__device__ __forceinline__ void split1(float v, ushort_t& h, ushort_t& l) {
    h = f2bf(v);
    l = f2bf(v - bf2f(h));
}
__device__ __forceinline__ void load_lds16(const void* g, void* l) {
    __builtin_amdgcn_global_load_lds(
        (const __attribute__((address_space(1))) unsigned int*)g,
        (__attribute__((address_space(3))) unsigned int*)l, 16, 0, 0);
}

// ---------------------------------------------------------------------------
// Split fp32 -> bf16 hi/lo pair.
// MODE 0: A plain      (lda)
// MODE 2: shift1(A)    (row t reads t-1 within each LSEQ batch)
// ---------------------------------------------------------------------------
template <int MODE>
__global__ __launch_bounds__(256) void split_bf16(
    const float* __restrict__ A,
    ushort_t* __restrict__ Hi, ushort_t* __restrict__ Lo,
    int M, int K, int lda)
{
    int K4 = K >> 2;
    long total = (long)M * K4;
    for (long i = (long)blockIdx.x * 256 + threadIdx.x; i < total;
         i += (long)gridDim.x * 256) {
        int m = (int)(i / K4);
        int k = (int)(i - (long)m * K4) * 4;
        float4 a;
        if (MODE == 2) {
            int t = m & (LSEQ - 1);
            if (t == 0) a = make_float4(0.f, 0.f, 0.f, 0.f);
            else        a = *(const float4*)(A + (size_t)(m - 1) * lda + k);
        } else {
            a = *(const float4*)(A + (size_t)m * lda + k);
        }
        ushort4 hv, lv;
        split1(a.x, hv.x, lv.x);
        split1(a.y, hv.y, lv.y);
        split1(a.z, hv.z, lv.z);
        split1(a.w, hv.w, lv.w);
        *(ushort4*)(Hi + (size_t)m * K + k) = hv;
        *(ushort4*)(Lo + (size_t)m * K + k) = lv;
    }
}

// ---------------------------------------------------------------------------
// Split-bf16 MFMA GEMM, 64(M) x 128(N) tile, BK=32, 256 threads = 4 waves
// (2x2, each wave 32x64). PROD3: 3 products (hh,hl,lh); else 2 (hh,hl).
// Split-K via gridDim.z (EOP 0 only).
// EOP: 0 C = acc
//      2 C = softplus(acc + E2[n])                (bias vector)
//      3 g = silu(E[m][n]+acc) * E2[m][n]; split -> Chi/Clo
//      4 split(acc) -> Chi/Clo
//      5 u-GEMM: gn<NC -> C = acc (+E[m][gn] if E); NC<=gn<NC+32 -> P[m][gn-NC]
// ---------------------------------------------------------------------------
template <int EOP, int PROD3>
__global__ __launch_bounds__(256, 4) void mfma_gemm(
    const ushort_t* __restrict__ Ahi, const ushort_t* __restrict__ Alo,
    const ushort_t* __restrict__ Whi, const ushort_t* __restrict__ Wlo,
    const float* __restrict__ E, const float* __restrict__ E2,
    float* __restrict__ C, ushort_t* __restrict__ Chi, ushort_t* __restrict__ Clo,
    float* __restrict__ P, int NC,
    int M, int N, int K, int ldE, int ldE2, int ldc)
{
    __shared__ __align__(16) short lds[12288];   // 24 KB
    short* sAhi = lds;            // 64 x 32
    short* sAlo = lds + 2048;
    short* sWhi = lds + 4096;     // 128 x 32
    short* sWlo = lds + 8192;
    char* lc = (char*)lds;

    const int tid = threadIdx.x, lane = tid & 63, w = tid >> 6;
    const int m0 = blockIdx.y * 64, n0 = blockIdx.x * 128;
    const int wm = (w & 1) * 32, wn = (w >> 1) * 64;

    const int ksub = K / gridDim.z;
    const int kbeg = blockIdx.z * ksub;
    if (gridDim.z > 1) C += (size_t)blockIdx.z * M * ldc;

    f32x4 zero4 = {0.f, 0.f, 0.f, 0.f};
    f32x4 acc[2][4];
    #pragma unroll
    for (int mi = 0; mi < 2; ++mi)
        #pragma unroll
        for (int ni = 0; ni < 4; ++ni) acc[mi][ni] = zero4;

    const int srow = w * 16 + (lane >> 2);   // [0,64)
    const int sk   = (lane & 3) * 8;
    size_t aoff  = (size_t)(m0 + srow) * K + kbeg + sk;
    size_t woff0 = (size_t)(n0 + srow) * K + kbeg + sk;
    size_t woff1 = (size_t)(n0 + srow + 64) * K + kbeg + sk;
    const int dstw = w * 1024;               // byte offset inside each 4 KB piece

    const int abase = (wm + (lane & 15)) * 32 + (lane >> 4) * 8;
    const int bbase = (wn + (lane & 15)) * 32 + (lane >> 4) * 8;

    for (int k0 = 0; k0 < ksub; k0 += 32) {
        load_lds16(Ahi + aoff, lc + dstw);                    // sAhi [0,4K)
        load_lds16(Alo + aoff, lc + 4096 + dstw);             // sAlo [4K,8K)
        load_lds16(Whi + woff0, lc + 8192 + dstw);            // sWhi rows 0-63
        load_lds16(Whi + woff1, lc + 8192 + 4096 + dstw);     // sWhi rows 64-127
        load_lds16(Wlo + woff0, lc + 16384 + dstw);
        load_lds16(Wlo + woff1, lc + 16384 + 4096 + dstw);
        aoff += 32; woff0 += 32; woff1 += 32;
        __syncthreads();

        bf16x8 ah[2], al[2], bh[4], bl[4];
        #pragma unroll
        for (int mi = 0; mi < 2; ++mi) {
            ah[mi] = *(const bf16x8*)(sAhi + abase + mi * 512);
            al[mi] = *(const bf16x8*)(sAlo + abase + mi * 512);
        }
        #pragma unroll
        for (int ni = 0; ni < 4; ++ni) {
            bh[ni] = *(const bf16x8*)(sWhi + bbase + ni * 512);
            bl[ni] = *(const bf16x8*)(sWlo + bbase + ni * 512);
        }
        #pragma unroll
        for (int mi = 0; mi < 2; ++mi)
            #pragma unroll
            for (int ni = 0; ni < 4; ++ni) {
                acc[mi][ni] = __builtin_amdgcn_mfma_f32_16x16x32_bf16(ah[mi], bh[ni], acc[mi][ni], 0, 0, 0);
                acc[mi][ni] = __builtin_amdgcn_mfma_f32_16x16x32_bf16(ah[mi], bl[ni], acc[mi][ni], 0, 0, 0);
                if (PROD3)
                    acc[mi][ni] = __builtin_amdgcn_mfma_f32_16x16x32_bf16(al[mi], bh[ni], acc[mi][ni], 0, 0, 0);
            }
        __syncthreads();
    }

    // C/D layout: col = lane&15, row = (lane>>4)*4 + reg
    const int col = lane & 15, rb = (lane >> 4) * 4;
    #pragma unroll
    for (int mi = 0; mi < 2; ++mi) {
        #pragma unroll
        for (int r = 0; r < 4; ++r) {
            int gm = m0 + wm + mi * 16 + rb + r;
            #pragma unroll
            for (int ni = 0; ni < 4; ++ni) {
                int gn = n0 + wn + ni * 16 + col;
                float v = acc[mi][ni][r];
                if (EOP == 0) {
                    C[(size_t)gm * ldc + gn] = v;
                } else if (EOP == 2) {
                    v += E2[gn];
                    v = (v > 20.f) ? v : log1pf(expf(v));
                    C[(size_t)gm * ldc + gn] = v;
                } else if (EOP == 3) {
                    float z2 = E[(size_t)gm * ldE + gn] + v;
                    float s = 1.f / (1.f + __expf(-z2));
                    float g = z2 * s * E2[(size_t)gm * ldE2 + gn];
                    ushort_t h, l;
                    split1(g, h, l);
                    Chi[(size_t)gm * ldc + gn] = h;
                    Clo[(size_t)gm * ldc + gn] = l;
                } else if (EOP == 4) {
                    ushort_t h, l;
                    split1(v, h, l);
                    Chi[(size_t)gm * ldc + gn] = h;
                    Clo[(size_t)gm * ldc + gn] = l;
                } else {  // EOP == 5
                    if (gn < NC) {
                        if (E) v += E[(size_t)gm * ldE + gn];
                        C[(size_t)gm * ldc + gn] = v;
                    } else if (gn < NC + 32) {
                        P[(size_t)gm * 32 + (gn - NC)] = v;
                    }
                }
            }
        }
    }
}

// xdbl[m][n] = sum_z Pd[z][m][128+n], n < 96
__global__ __launch_bounds__(256) void reduce_xdbl(
    const float* __restrict__ Pd, float* __restrict__ xdbl)
{
    int idx = blockIdx.x * 256 + threadIdx.x;
    if (idx >= NTOK * XDBL_N) return;
    int m = idx / XDBL_N, n = idx - m * XDBL_N;
    float s = 0.f;
    #pragma unroll
    for (int zz = 0; zz < 8; ++zz)
        s += Pd[(size_t)zz * NTOK * 128 + (size_t)m * 128 + n];
    xdbl[(size_t)m * XDBL_N + n] = s;
}

// ---------------------------------------------------------------------------
// Bt/Ct[t+1] = normalize(B0C0[t+1] + xWbc[t] - P[t])
// ---------------------------------------------------------------------------
__global__ __launch_bounds__(256) void bc_make(
    const float* __restrict__ xdbl, const float* __restrict__ xWbc,
    const float* __restrict__ P, float* __restrict__ Btb, float* __restrict__ Ctb)
{
    int tok = blockIdx.x * 8 + (threadIdx.x >> 5);
    int j = threadIdx.x & 31;
    int t = tok & (LSEQ - 1);
    if (t == LSEQ - 1) return;   // no t+1 in this batch (full 32-lane groups exit)
    int tn = tok + 1;
    float v = xdbl[(size_t)tn * XDBL_N + DTR + j]
            + xWbc[(size_t)tok * 128 + j] - P[(size_t)tok * 32 + j];
    float sq = v * v;
    #pragma unroll
    for (int off = 8; off >= 1; off >>= 1) sq += __shfl_xor(sq, off, 16);
    float nrm = fmaxf(sqrtf(sq), EPSF);
    float outv = v / nrm;
    if (j < 16) Btb[(size_t)tn * NST + j] = outv;
    else        Ctb[(size_t)tn * NST + (j - 16)] = outv;
}

// ---------------------------------------------------------------------------
// Chunked selective scan.
// ---------------------------------------------------------------------------
__global__ __launch_bounds__(256) void scan_pass1(
    const float* __restrict__ delta, const float* __restrict__ u,
    const float* __restrict__ Bt, const float* __restrict__ Alog,
    float* __restrict__ Ac, float* __restrict__ Hend)
{
    int d = blockIdx.x * 256 + threadIdx.x;
    int c = blockIdx.y, b = blockIdx.z;
    int t0 = c * CS;
    __shared__ float sB[CS][NST];
    for (int i = threadIdx.x; i < CS * NST; i += 256)
        ((float*)sB)[i] = Bt[(size_t)(b * LSEQ + t0) * NST + i];
    __syncthreads();

    float Avals[NST];
    #pragma unroll
    for (int n = 0; n < NST; ++n) Avals[n] = -__expf(Alog[d * NST + n]);
    float h[NST] = {};
    float Pp[NST];
    #pragma unroll
    for (int n = 0; n < NST; ++n) Pp[n] = 1.f;

    const float* dptr = delta + (size_t)(b * LSEQ + t0) * DI + d;
    const float* uptr = u + (size_t)(b * LSEQ + t0) * DI + d;
    for (int tt = 0; tt < CS; ++tt) {
        float dt = dptr[(size_t)tt * DI];
        float ut = uptr[(size_t)tt * DI];
        float wv = dt * ut;
        #pragma unroll
        for (int n = 0; n < NST; ++n) {
            float a = __expf(dt * Avals[n]);
            Pp[n] *= a;
            h[n] = fmaf(a, h[n], wv * sB[tt][n]);
        }
    }
    size_t o = ((size_t)((b * NCH + c) * DI) + d) * NST;
    #pragma unroll
    for (int n = 0; n < NST; ++n) { Ac[o + n] = Pp[n]; Hend[o + n] = h[n]; }
}

__global__ __launch_bounds__(256) void scan_pass2(
    float* __restrict__ Ac, const float* __restrict__ Hend)
{
    int idx = blockIdx.x * 256 + threadIdx.x;
    int b = idx / (DI * NST);
    int dn = idx % (DI * NST);
    float h = 0.f;
    for (int c = 0; c < NCH; ++c) {
        size_t o = (size_t)(b * NCH + c) * DI * NST + dn;
        float a = Ac[o];
        float e = Hend[o];
        Ac[o] = h;               // Hin in place
        h = fmaf(a, h, e);
    }
}

__global__ __launch_bounds__(256) void scan_pass3(
    const float* __restrict__ delta, const float* u,
    const float* __restrict__ Bt, const float* __restrict__ Ct,
    const float* __restrict__ Alog, const float* __restrict__ Dp,
    const float* __restrict__ Hin, float* yraw)  // yraw may alias u
{
    int d = blockIdx.x * 256 + threadIdx.x;
    int c = blockIdx.y, b = blockIdx.z;
    int t0 = c * CS;
    __shared__ float sB[CS][NST];
    __shared__ float sC[CS][NST];
    for (int i = threadIdx.x; i < CS * NST; i += 256) {
        ((float*)sB)[i] = Bt[(size_t)(b * LSEQ + t0) * NST + i];
        ((float*)sC)[i] = Ct[(size_t)(b * LSEQ + t0) * NST + i];
    }
    __syncthreads();

    float Avals[NST];
    #pragma unroll
    for (int n = 0; n < NST; ++n) Avals[n] = -__expf(Alog[d * NST + n]);
    float h[NST];
    size_t o = ((size_t)((b * NCH + c) * DI) + d) * NST;
    #pragma unroll
    for (int n = 0; n < NST; ++n) h[n] = Hin[o + n];
    float Dd = Dp[d];

    const float* dptr = delta + (size_t)(b * LSEQ + t0) * DI + d;
    const float* uptr = u + (size_t)(b * LSEQ + t0) * DI + d;
    float* yptr = yraw + (size_t)(b * LSEQ + t0) * DI + d;
    for (int tt = 0; tt < CS; ++tt) {
        float dt = dptr[(size_t)tt * DI];
        float ut = uptr[(size_t)tt * DI];
        float wv = dt * ut;
        float acc = 0.f;
        #pragma unroll
        for (int n = 0; n < NST; ++n) {
            float a = __expf(dt * Avals[n]);
            h[n] = fmaf(a, h[n], wv * sB[tt][n]);
            acc = fmaf(h[n], sC[tt][n], acc);
        }
        yptr[(size_t)tt * DI] = fmaf(Dd, ut, acc);
    }
}

// ---------------------------------------------------------------------------
// Per-token LN -> fp update (in place) -> split(x - y_next) for next u-GEMM.
// ---------------------------------------------------------------------------
__global__ __launch_bounds__(256) void ln_update(
    const float* __restrict__ yraw, float* __restrict__ ybuf,
    const float* __restrict__ gamma, const float* __restrict__ beta,
    const ushort_t* __restrict__ XHi, const ushort_t* __restrict__ XLo,
    ushort_t* __restrict__ AuHi, ushort_t* __restrict__ AuLo,
    int is_first, int is_final)
{
    int t = blockIdx.x, b = blockIdx.y;
    int tid = threadIdx.x;
    size_t ro = (size_t)(b * LSEQ + t) * DI;
    const float* yr = yraw + ro;
    float* yp = ybuf + ro;

    float s = 0.f, s2 = 0.f;
    float vloc[DI / 256];
    #pragma unroll
    for (int i = 0; i < DI / 256; ++i) {
        float v = yr[tid + i * 256];
        vloc[i] = v; s += v; s2 += v * v;
    }
    #pragma unroll
    for (int off = 32; off >= 1; off >>= 1) {
        s += __shfl_down(s, off, 64);
        s2 += __shfl_down(s2, off, 64);
    }
    __shared__ float rs[4], rs2[4];
    __shared__ float smean, srstd;
    int wid = tid >> 6, lane = tid & 63;
    if (lane == 0) { rs[wid] = s; rs2[wid] = s2; }
    __syncthreads();
    if (tid == 0) {
        float S = rs[0] + rs[1] + rs[2] + rs[3];
        float S2 = rs2[0] + rs2[1] + rs2[2] + rs2[3];
        float m = S / (float)DI;
        float var = S2 / (float)DI - m * m;
        smean = m;
        srstd = rsqrtf(var + EPSF);
    }
    __syncthreads();
    float m = smean, r = srstd;

    #pragma unroll
    for (int i = 0; i < DI / 256; ++i) {
        int idx = tid + i * 256;
        float ln = (vloc[i] - m) * r * gamma[idx] + beta[idx];
        float ypv = is_first ? 0.f : yp[idx];
        float yn = is_final ? ln : fmaf(STEPF, ln - ypv, ypv);
        yp[idx] = yn;
        if (!is_final) {
            float xv = bf2f(XHi[ro + idx]) + bf2f(XLo[ro + idx]);
            ushort_t h, l;
            split1(xv - yn, h, l);
            AuHi[ro + idx] = h;
            AuLo[ro + idx] = l;
        }
    }
}

__global__ __launch_bounds__(256) void bc_init(
    const float* __restrict__ xdbl, float* __restrict__ Btb, float* __restrict__ Ctb)
{
    int tok = blockIdx.x * 8 + (threadIdx.x >> 5);
    int i = threadIdx.x & 31;
    float v = xdbl[(size_t)tok * XDBL_N + DTR + i];
    float sq = v * v;
    #pragma unroll
    for (int off = 8; off >= 1; off >>= 1) sq += __shfl_xor(sq, off, 16);
    float nrm = fmaxf(sqrtf(sq), EPSF);
    float outv = v / nrm;
    if (i < 16) Btb[(size_t)tok * NST + i] = outv;
    else        Ctb[(size_t)tok * NST + (i - 16)] = outv;
}

__global__ __launch_bounds__(256) void fill_zero(float* p, size_t n)
{
    size_t i = (size_t)blockIdx.x * blockDim.x + threadIdx.x;
    size_t stride = (size_t)gridDim.x * blockDim.x;
    for (; i < n; i += stride) p[i] = 0.f;
}

// ---------------------------------------------------------------------------
extern "C" void kernel_launch(void* const* d_in, const int* in_sizes, int n_in,
                              void* d_out, int out_size, void* d_ws, size_t ws_size,
                              hipStream_t stream)
{
    const float* hs    = (const float*)d_in[0];
    const float* W_in  = (const float*)d_in[1];
    const float* W_x   = (const float*)d_in[2];
    const float* W_dt  = (const float*)d_in[3];
    const float* b_dt  = (const float*)d_in[4];
    const float* A_log = (const float*)d_in[5];
    const float* W_bc  = (const float*)d_in[6];
    const float* W_zy  = (const float*)d_in[7];
    const float* W_mix = (const float*)d_in[8];
    const float* Dp    = (const float*)d_in[9];
    const float* g_ln  = (const float*)d_in[10];
    const float* b_ln  = (const float*)d_in[11];
    const float* W_out = (const float*)d_in[12];
    float* out = (float*)d_out;

    char* ws = (char*)d_ws;
    size_t off = 0;
    auto alloc = [&](size_t bytes) {
        void* p = (void*)(ws + off);
        off += (bytes + 255) & ~(size_t)255;
        return p;
    };
    float*    z      = (float*)alloc((size_t)NTOK * DI * 4);       // 32 MB
    ushort_t* XHi    = (ushort_t*)alloc((size_t)NTOK * DI * 2);    // 16 MB (epilogue: shift1(y) hi)
    ushort_t* XLo    = (ushort_t*)alloc((size_t)NTOK * DI * 2);    // 16 MB
    float*    delta  = (float*)alloc((size_t)NTOK * DI * 4);       // 32 MB (epilogue: Ghi|Glo)
    float*    ubuf   = (float*)alloc((size_t)NTOK * DI * 4);       // 32 MB (prologue: hs/Win splits)
    float*    yA     = (float*)alloc((size_t)NTOK * DI * 4);       // 32 MB (prologue: Pd + Xd splits)
    ushort_t* AuHi   = (ushort_t*)alloc((size_t)NTOK * DI * 2);    // 16 MB (prologue: Wx split)
    ushort_t* AuLo   = (ushort_t*)alloc((size_t)NTOK * DI * 2);    // 16 MB (prologue: Wdt split)
    ushort_t* WextHi = (ushort_t*)alloc((size_t)NEXT * DI * 2);    // 8.5 MB (epilogue: Wzy hi)
    ushort_t* WextLo = (ushort_t*)alloc((size_t)NEXT * DI * 2);    // 8.5 MB (epilogue: Wzy lo)
    float*    Ac     = (float*)alloc((size_t)B_SZ * NCH * DI * NST * 4); // 8 MB (epilogue: Wout hi)
    float*    Hend   = (float*)alloc((size_t)B_SZ * NCH * DI * NST * 4); // 8 MB (epilogue: Wout lo)
    float*    xdbl   = (float*)alloc((size_t)NTOK * XDBL_N * 4);   // 1.5 MB
    float*    Btb    = (float*)alloc((size_t)NTOK * NST * 4);
    float*    Ctb    = (float*)alloc((size_t)NTOK * NST * 4);
    float*    Pbuf   = (float*)alloc((size_t)NTOK * 32 * 4);       // 0.5 MB
    float*    xWbc   = (float*)alloc((size_t)NTOK * 128 * 4);      // 2 MB

    // prologue aliases
    ushort_t* HsHi  = (ushort_t*)ubuf;
    ushort_t* HsLo  = HsHi + (size_t)NTOK * DM;
    ushort_t* WinHi = HsLo + (size_t)NTOK * DM;
    ushort_t* WinLo = WinHi + (size_t)(2 * DI) * DM;               // = 32 MB exactly
    float*    Pd    = yA;                                          // 8 x 4096 x 128 = 16 MB
    ushort_t* XdHi  = (ushort_t*)(yA + (size_t)NTOK * DI / 2);     // yA + 16 MB
    ushort_t* XdLo  = XdHi + (size_t)NTOK * DTR;
    ushort_t* WxHi  = AuHi;                                        // 128 x 2048 bf16
    ushort_t* WxLo  = WxHi + (size_t)128 * DI;
    ushort_t* WdtHi = AuLo;                                        // 2048 x 64 bf16
    ushort_t* WdtLo = WdtHi + (size_t)DI * DTR;
    // epilogue aliases
    ushort_t* Ghi   = (ushort_t*)delta;
    ushort_t* Glo   = Ghi + (size_t)NTOK * DI;
    ushort_t* WzyHi = WextHi;
    ushort_t* WzyLo = WextLo;
    ushort_t* WoutHi= (ushort_t*)Ac;
    ushort_t* WoutLo= (ushort_t*)Hend;
    float*    yraw  = ubuf;

    dim3 blk(256);

    // --- prologue: splits ---
    split_bf16<0><<<4096, blk, 0, stream>>>(hs, HsHi, HsLo, NTOK, DM, DM);
    split_bf16<0><<<4096, blk, 0, stream>>>(W_in, WinHi, WinLo, 2 * DI, DM, DM);
    fill_zero<<<64, blk, 0, stream>>>((float*)WxHi, (size_t)128 * DI / 2);
    fill_zero<<<64, blk, 0, stream>>>((float*)WxLo, (size_t)128 * DI / 2);
    split_bf16<0><<<512, blk, 0, stream>>>(W_x, WxHi, WxLo, XDBL_N, DI, DI);
    split_bf16<0><<<128, blk, 0, stream>>>(W_dt, WdtHi, WdtLo, DI, DTR, DTR);
    // Wext = [W_mix rows 0..2047 | W_bc rows 2048..2079 | zeros 2080..2175]
    split_bf16<0><<<4096, blk, 0, stream>>>(W_mix, WextHi, WextLo, DI, DI, DI);
    fill_zero<<<128, blk, 0, stream>>>((float*)(WextHi + (size_t)DI * DI), (size_t)128 * DI / 2);
    fill_zero<<<128, blk, 0, stream>>>((float*)(WextLo + (size_t)DI * DI), (size_t)128 * DI / 2);
    split_bf16<0><<<64, blk, 0, stream>>>(W_bc, WextHi + (size_t)DI * DI,
                                          WextLo + (size_t)DI * DI, 32, DI, DI);

    // x = hs @ W_in[:DI]^T (split out), z = hs @ W_in[DI:]^T (fp32)
    mfma_gemm<4, 1><<<dim3(DI / 128, NTOK / 64), blk, 0, stream>>>(
        HsHi, HsLo, WinHi, WinLo, nullptr, nullptr, nullptr, XHi, XLo,
        nullptr, 0, NTOK, DI, DM, 0, 0, DI);
    mfma_gemm<0, 1><<<dim3(DI / 128, NTOK / 64), blk, 0, stream>>>(
        HsHi, HsLo, WinHi + (size_t)DI * DM, WinLo + (size_t)DI * DM,
        nullptr, nullptr, z, nullptr, nullptr, nullptr, 0, NTOK, DI, DM, 0, 0, DI);

    // xdbl: split-K (8) over K=DI, N padded to 128
    mfma_gemm<0, 1><<<dim3(1, NTOK / 64, 8), blk, 0, stream>>>(
        XHi, XLo, WxHi, WxLo, nullptr, nullptr, Pd, nullptr, nullptr,
        nullptr, 0, NTOK, 128, DI, 0, 0, 128);
    reduce_xdbl<<<(NTOK * XDBL_N + 255) / 256, blk, 0, stream>>>(Pd, xdbl);

    // delta = softplus(dt_low @ W_dt^T + b_dt)
    split_bf16<0><<<256, blk, 0, stream>>>(xdbl, XdHi, XdLo, NTOK, DTR, XDBL_N);
    mfma_gemm<2, 1><<<dim3(DI / 128, NTOK / 64), blk, 0, stream>>>(
        XdHi, XdLo, WdtHi, WdtLo, nullptr, b_dt, delta, nullptr, nullptr,
        nullptr, 0, NTOK, DI, DTR, 0, 0, DI);

    bc_init<<<NTOK / 8, 256, 0, stream>>>(xdbl, Btb, Ctb);

    // xWbc = x @ Wext[2048:2176]^T  (once; cols 0..31 = x @ W_bc^T)
    mfma_gemm<0, 1><<<dim3(1, NTOK / 64), blk, 0, stream>>>(
        XHi, XLo, WextHi + (size_t)DI * DI, WextLo + (size_t)DI * DI,
        nullptr, nullptr, xWbc, nullptr, nullptr, nullptr, 0,
        NTOK, 128, DI, 0, 0, 128);

    // --- fixed-point loop ---
    for (int it = 0; it <= FP_ITERS; ++it) {
        const ushort_t* Ah = (it == 0) ? XHi : AuHi;
        const ushort_t* Al = (it == 0) ? XLo : AuLo;
        const float* Ey = (it == 0) ? nullptr : yA;
        if (it <= 3) {
            mfma_gemm<5, 0><<<dim3(NEXT / 128, NTOK / 64), blk, 0, stream>>>(
                Ah, Al, WextHi, WextLo, Ey, nullptr, ubuf, nullptr, nullptr,
                Pbuf, DI, NTOK, NEXT, DI, DI, 0, DI);
        } else {
            mfma_gemm<5, 1><<<dim3(NEXT / 128, NTOK / 64), blk, 0, stream>>>(
                Ah, Al, WextHi, WextLo, Ey, nullptr, ubuf, nullptr, nullptr,
                Pbuf, DI, NTOK, NEXT, DI, DI, 0, DI);
        }
        bc_make<<<NTOK / 8, blk, 0, stream>>>(xdbl, xWbc, Pbuf, Btb, Ctb);
        scan_pass1<<<dim3(DI / 256, NCH, B_SZ), blk, 0, stream>>>(
            delta, ubuf, Btb, A_log, Ac, Hend);
        scan_pass2<<<dim3(B_SZ * DI * NST / 256), blk, 0, stream>>>(Ac, Hend);
        scan_pass3<<<dim3(DI / 256, NCH, B_SZ), blk, 0, stream>>>(
            delta, ubuf, Btb, Ctb, A_log, Dp, Ac, yraw);
        ln_update<<<dim3(LSEQ, B_SZ), blk, 0, stream>>>(
            yraw, yA, g_ln, b_ln, XHi, XLo, AuHi, AuLo,
            it == 0 ? 1 : 0, it == FP_ITERS ? 1 : 0);
    }

    // --- epilogue ---
    // g = silu(z + shift1(y) @ W_zy^T) * y   (split into delta buf)
    split_bf16<2><<<8192, blk, 0, stream>>>(yA, XHi, XLo, NTOK, DI, DI);
    split_bf16<0><<<4096, blk, 0, stream>>>(W_zy, WzyHi, WzyLo, DI, DI, DI);
    mfma_gemm<3, 1><<<dim3(DI / 128, NTOK / 64), blk, 0, stream>>>(
        XHi, XLo, WzyHi, WzyLo, z, yA, nullptr, Ghi, Glo, nullptr, 0,
        NTOK, DI, DI, DI, DI, DI);

    // out = g @ W_out^T
    split_bf16<0><<<2048, blk, 0, stream>>>(W_out, WoutHi, WoutLo, DM, DI, DI);
    mfma_gemm<0, 1><<<dim3(DM / 128, NTOK / 64), blk, 0, stream>>>(
        Ghi, Glo, WoutHi, WoutLo, nullptr, nullptr, out, nullptr, nullptr,
        nullptr, 0, NTOK, DM, DI, 0, 0, DM);
}

// Round 5
// 2933.507 us; speedup vs baseline: 1.1839x; 1.1839x over previous
//
#include <hip/hip_runtime.h>
#include <math.h>

#define B_SZ   2
#define LSEQ   2048
#define DM     1024
#define DI     2048
#define NST    16
#define DTR    64
#define XDBL_N 96
#define NTOK   (B_SZ * LSEQ)
#define NCH    32
#define CS     64
#define EPSF   1e-5f
#define STEPF  0.99f
#define FP_ITERS 8
#define NEXT   2176   // DI + 128 (32 Wbc cols + 96 pad)

typedef __attribute__((ext_vector_type(8))) short bf16x8;
typedef __attribute__((ext_vector_type(4))) float f32x4;
typedef unsigned short ushort_t;

__device__ __forceinline__ ushort_t f2bf(float v) {
    unsigned u = __float_as_uint(v);
    unsigned r = (u + 0x7fffu + ((u >> 16) & 1u)) >> 16;   // RNE
    return (ushort_t)r;
}
__device__ __forceinline__ float bf2f(ushort_t h) {
    return __uint_as_float(((unsigned)h) << 16);
}
__device__ __forceinline__ void split1(float v, ushort_t& h, ushort_t& l) {
    h = f2bf(v);
    l = f2bf(v - bf2f(h));
}
__device__ __forceinline__ void load_lds16(const void* g, void* l) {
    __builtin_amdgcn_global_load_lds(
        (const __attribute__((address_space(1))) unsigned int*)g,
        (__attribute__((address_space(3))) unsigned int*)l, 16, 0, 0);
}

// ---------------------------------------------------------------------------
// Split fp32 -> bf16 hi/lo pair.
// MODE 0: A plain      (lda)
// MODE 2: shift1(A)    (row t reads t-1 within each LSEQ batch)
// ---------------------------------------------------------------------------
template <int MODE>
__global__ __launch_bounds__(256) void split_bf16(
    const float* __restrict__ A,
    ushort_t* __restrict__ Hi, ushort_t* __restrict__ Lo,
    int M, int K, int lda)
{
    int K4 = K >> 2;
    long total = (long)M * K4;
    for (long i = (long)blockIdx.x * 256 + threadIdx.x; i < total;
         i += (long)gridDim.x * 256) {
        int m = (int)(i / K4);
        int k = (int)(i - (long)m * K4) * 4;
        float4 a;
        if (MODE == 2) {
            int t = m & (LSEQ - 1);
            if (t == 0) a = make_float4(0.f, 0.f, 0.f, 0.f);
            else        a = *(const float4*)(A + (size_t)(m - 1) * lda + k);
        } else {
            a = *(const float4*)(A + (size_t)m * lda + k);
        }
        ushort4 hv, lv;
        split1(a.x, hv.x, lv.x);
        split1(a.y, hv.y, lv.y);
        split1(a.z, hv.z, lv.z);
        split1(a.w, hv.w, lv.w);
        *(ushort4*)(Hi + (size_t)m * K + k) = hv;
        *(ushort4*)(Lo + (size_t)m * K + k) = lv;
    }
}

// ---------------------------------------------------------------------------
// Split-bf16 MFMA GEMM, 128x128 tile, BK=32, 256 threads = 4 waves (2x2 of
// 64x64). PROD3: 3 products (hh,hl,lh) vs 2 (hh,hl). Split-K via gridDim.z.
// Grid must be (N/128, M/128[, splitk]); co-residency (<=1024 blocks) keeps
// the K-slice streaming hot in L2 — do NOT shrink the M tile (round-4 lesson).
// EOP: 0 C = acc
//      2 C = softplus(acc + E2[n])                (bias vector)
//      3 g = silu(E[m][n]+acc) * E2[m][n]; split -> Chi/Clo
//      4 split(acc) -> Chi/Clo
//      5 u-GEMM: gn<NC -> C = acc (+E[m][gn] if E); NC<=gn<NC+32 -> P[m][gn-NC]
// ---------------------------------------------------------------------------
template <int EOP, int PROD3>
__global__ __launch_bounds__(256) void mfma_gemm(
    const ushort_t* __restrict__ Ahi, const ushort_t* __restrict__ Alo,
    const ushort_t* __restrict__ Whi, const ushort_t* __restrict__ Wlo,
    const float* __restrict__ E, const float* __restrict__ E2,
    float* __restrict__ C, ushort_t* __restrict__ Chi, ushort_t* __restrict__ Clo,
    float* __restrict__ P, int NC,
    int M, int N, int K, int ldE, int ldE2, int ldc)
{
    __shared__ __align__(16) short lds[16384];  // 32 KB: Ahi|Alo|Whi|Wlo, each 128x32
    short* sAhi = lds;
    short* sAlo = lds + 4096;
    short* sWhi = lds + 8192;
    short* sWlo = lds + 12288;
    char* ldsc = (char*)lds;

    const int tid = threadIdx.x, lane = tid & 63, w = tid >> 6;
    const int m0 = blockIdx.y * 128, n0 = blockIdx.x * 128;
    const int wm = (w & 1) * 64, wn = (w >> 1) * 64;

    const int ksub = K / gridDim.z;
    const int kbeg = blockIdx.z * ksub;
    if (gridDim.z > 1) C += (size_t)blockIdx.z * M * ldc;

    f32x4 zero4 = {0.f, 0.f, 0.f, 0.f};
    f32x4 acc[4][4];
    #pragma unroll
    for (int mi = 0; mi < 4; ++mi)
        #pragma unroll
        for (int ni = 0; ni < 4; ++ni) acc[mi][ni] = zero4;

    size_t aoff[2], woff[2];
    #pragma unroll
    for (int i = 0; i < 2; ++i) {
        int j = w * 2 + i;
        int row = j * 16 + (lane >> 2);
        int ke = (lane & 3) * 8;
        aoff[i] = (size_t)(m0 + row) * K + kbeg + ke;
        woff[i] = (size_t)(n0 + row) * K + kbeg + ke;
    }
    const int abase = (wm + (lane & 15)) * 32 + (lane >> 4) * 8;
    const int bbase = (wn + (lane & 15)) * 32 + (lane >> 4) * 8;

    for (int k0 = 0; k0 < ksub; k0 += 32) {
        #pragma unroll
        for (int i = 0; i < 2; ++i) {
            int dst = (w * 2 + i) * 1024;
            load_lds16(Ahi + aoff[i], ldsc + dst);
            load_lds16(Alo + aoff[i], ldsc + 8192 + dst);
            load_lds16(Whi + woff[i], ldsc + 16384 + dst);
            load_lds16(Wlo + woff[i], ldsc + 24576 + dst);
            aoff[i] += 32; woff[i] += 32;
        }
        __syncthreads();

        bf16x8 ah[4], al[4], bh[4], bl[4];
        #pragma unroll
        for (int mi = 0; mi < 4; ++mi) {
            ah[mi] = *(const bf16x8*)(sAhi + abase + mi * 512);
            al[mi] = *(const bf16x8*)(sAlo + abase + mi * 512);
        }
        #pragma unroll
        for (int ni = 0; ni < 4; ++ni) {
            bh[ni] = *(const bf16x8*)(sWhi + bbase + ni * 512);
            bl[ni] = *(const bf16x8*)(sWlo + bbase + ni * 512);
        }
        #pragma unroll
        for (int mi = 0; mi < 4; ++mi)
            #pragma unroll
            for (int ni = 0; ni < 4; ++ni) {
                acc[mi][ni] = __builtin_amdgcn_mfma_f32_16x16x32_bf16(ah[mi], bh[ni], acc[mi][ni], 0, 0, 0);
                acc[mi][ni] = __builtin_amdgcn_mfma_f32_16x16x32_bf16(ah[mi], bl[ni], acc[mi][ni], 0, 0, 0);
                if (PROD3)
                    acc[mi][ni] = __builtin_amdgcn_mfma_f32_16x16x32_bf16(al[mi], bh[ni], acc[mi][ni], 0, 0, 0);
            }
        __syncthreads();
    }

    // C/D layout: col = lane&15, row = (lane>>4)*4 + reg
    const int col = lane & 15, rb = (lane >> 4) * 4;
    #pragma unroll
    for (int mi = 0; mi < 4; ++mi) {
        #pragma unroll
        for (int r = 0; r < 4; ++r) {
            int gm = m0 + wm + mi * 16 + rb + r;
            #pragma unroll
            for (int ni = 0; ni < 4; ++ni) {
                int gn = n0 + wn + ni * 16 + col;
                float v = acc[mi][ni][r];
                if (EOP == 0) {
                    C[(size_t)gm * ldc + gn] = v;
                } else if (EOP == 2) {
                    v += E2[gn];
                    v = (v > 20.f) ? v : log1pf(expf(v));
                    C[(size_t)gm * ldc + gn] = v;
                } else if (EOP == 3) {
                    float z2 = E[(size_t)gm * ldE + gn] + v;
                    float s = 1.f / (1.f + __expf(-z2));
                    float g = z2 * s * E2[(size_t)gm * ldE2 + gn];
                    ushort_t h, l;
                    split1(g, h, l);
                    Chi[(size_t)gm * ldc + gn] = h;
                    Clo[(size_t)gm * ldc + gn] = l;
                } else if (EOP == 4) {
                    ushort_t h, l;
                    split1(v, h, l);
                    Chi[(size_t)gm * ldc + gn] = h;
                    Clo[(size_t)gm * ldc + gn] = l;
                } else {  // EOP == 5
                    if (gn < NC) {
                        if (E) v += E[(size_t)gm * ldE + gn];
                        C[(size_t)gm * ldc + gn] = v;
                    } else if (gn < NC + 32) {
                        P[(size_t)gm * 32 + (gn - NC)] = v;
                    }
                }
            }
        }
    }
}

// xdbl[m][n] = sum_z Pd[z][m][128+n], n < 96
__global__ __launch_bounds__(256) void reduce_xdbl(
    const float* __restrict__ Pd, float* __restrict__ xdbl)
{
    int idx = blockIdx.x * 256 + threadIdx.x;
    if (idx >= NTOK * XDBL_N) return;
    int m = idx / XDBL_N, n = idx - m * XDBL_N;
    float s = 0.f;
    #pragma unroll
    for (int zz = 0; zz < 8; ++zz)
        s += Pd[(size_t)zz * NTOK * 128 + (size_t)m * 128 + n];
    xdbl[(size_t)m * XDBL_N + n] = s;
}

// ---------------------------------------------------------------------------
// Bt/Ct[t+1] = normalize(B0C0[t+1] + xWbc[t] - P[t])
// ---------------------------------------------------------------------------
__global__ __launch_bounds__(256) void bc_make(
    const float* __restrict__ xdbl, const float* __restrict__ xWbc,
    const float* __restrict__ P, float* __restrict__ Btb, float* __restrict__ Ctb)
{
    int tok = blockIdx.x * 8 + (threadIdx.x >> 5);
    int j = threadIdx.x & 31;
    int t = tok & (LSEQ - 1);
    if (t == LSEQ - 1) return;
    int tn = tok + 1;
    float v = xdbl[(size_t)tn * XDBL_N + DTR + j]
            + xWbc[(size_t)tok * 128 + j] - P[(size_t)tok * 32 + j];
    float sq = v * v;
    #pragma unroll
    for (int off = 8; off >= 1; off >>= 1) sq += __shfl_xor(sq, off, 16);
    float nrm = fmaxf(sqrtf(sq), EPSF);
    float outv = v / nrm;
    if (j < 16) Btb[(size_t)tn * NST + j] = outv;
    else        Ctb[(size_t)tn * NST + (j - 16)] = outv;
}

// ---------------------------------------------------------------------------
// Chunked selective scan.
// ---------------------------------------------------------------------------
__global__ __launch_bounds__(256) void scan_pass1(
    const float* __restrict__ delta, const float* __restrict__ u,
    const float* __restrict__ Bt, const float* __restrict__ Alog,
    float* __restrict__ Ac, float* __restrict__ Hend)
{
    int d = blockIdx.x * 256 + threadIdx.x;
    int c = blockIdx.y, b = blockIdx.z;
    int t0 = c * CS;
    __shared__ float sB[CS][NST];
    for (int i = threadIdx.x; i < CS * NST; i += 256)
        ((float*)sB)[i] = Bt[(size_t)(b * LSEQ + t0) * NST + i];
    __syncthreads();

    float Avals[NST];
    #pragma unroll
    for (int n = 0; n < NST; ++n) Avals[n] = -__expf(Alog[d * NST + n]);
    float h[NST] = {};
    float Pp[NST];
    #pragma unroll
    for (int n = 0; n < NST; ++n) Pp[n] = 1.f;

    const float* dptr = delta + (size_t)(b * LSEQ + t0) * DI + d;
    const float* uptr = u + (size_t)(b * LSEQ + t0) * DI + d;
    for (int tt = 0; tt < CS; ++tt) {
        float dt = dptr[(size_t)tt * DI];
        float ut = uptr[(size_t)tt * DI];
        float wv = dt * ut;
        #pragma unroll
        for (int n = 0; n < NST; ++n) {
            float a = __expf(dt * Avals[n]);
            Pp[n] *= a;
            h[n] = fmaf(a, h[n], wv * sB[tt][n]);
        }
    }
    size_t o = ((size_t)((b * NCH + c) * DI) + d) * NST;
    #pragma unroll
    for (int n = 0; n < NST; ++n) { Ac[o + n] = Pp[n]; Hend[o + n] = h[n]; }
}

__global__ __launch_bounds__(256) void scan_pass2(
    float* __restrict__ Ac, const float* __restrict__ Hend)
{
    int idx = blockIdx.x * 256 + threadIdx.x;
    int b = idx / (DI * NST);
    int dn = idx % (DI * NST);
    float h = 0.f;
    for (int c = 0; c < NCH; ++c) {
        size_t o = (size_t)(b * NCH + c) * DI * NST + dn;
        float a = Ac[o];
        float e = Hend[o];
        Ac[o] = h;               // Hin in place
        h = fmaf(a, h, e);
    }
}

__global__ __launch_bounds__(256) void scan_pass3(
    const float* __restrict__ delta, const float* u,
    const float* __restrict__ Bt, const float* __restrict__ Ct,
    const float* __restrict__ Alog, const float* __restrict__ Dp,
    const float* __restrict__ Hin, float* yraw)  // yraw may alias u
{
    int d = blockIdx.x * 256 + threadIdx.x;
    int c = blockIdx.y, b = blockIdx.z;
    int t0 = c * CS;
    __shared__ float sB[CS][NST];
    __shared__ float sC[CS][NST];
    for (int i = threadIdx.x; i < CS * NST; i += 256) {
        ((float*)sB)[i] = Bt[(size_t)(b * LSEQ + t0) * NST + i];
        ((float*)sC)[i] = Ct[(size_t)(b * LSEQ + t0) * NST + i];
    }
    __syncthreads();

    float Avals[NST];
    #pragma unroll
    for (int n = 0; n < NST; ++n) Avals[n] = -__expf(Alog[d * NST + n]);
    float h[NST];
    size_t o = ((size_t)((b * NCH + c) * DI) + d) * NST;
    #pragma unroll
    for (int n = 0; n < NST; ++n) h[n] = Hin[o + n];
    float Dd = Dp[d];

    const float* dptr = delta + (size_t)(b * LSEQ + t0) * DI + d;
    const float* uptr = u + (size_t)(b * LSEQ + t0) * DI + d;
    float* yptr = yraw + (size_t)(b * LSEQ + t0) * DI + d;
    for (int tt = 0; tt < CS; ++tt) {
        float dt = dptr[(size_t)tt * DI];
        float ut = uptr[(size_t)tt * DI];
        float wv = dt * ut;
        float acc = 0.f;
        #pragma unroll
        for (int n = 0; n < NST; ++n) {
            float a = __expf(dt * Avals[n]);
            h[n] = fmaf(a, h[n], wv * sB[tt][n]);
            acc = fmaf(h[n], sC[tt][n], acc);
        }
        yptr[(size_t)tt * DI] = fmaf(Dd, ut, acc);
    }
}

// ---------------------------------------------------------------------------
// Per-token LN -> fp update (in place) -> split(x - y_next) for next u-GEMM.
// ---------------------------------------------------------------------------
__global__ __launch_bounds__(256) void ln_update(
    const float* __restrict__ yraw, float* __restrict__ ybuf,
    const float* __restrict__ gamma, const float* __restrict__ beta,
    const ushort_t* __restrict__ XHi, const ushort_t* __restrict__ XLo,
    ushort_t* __restrict__ AuHi, ushort_t* __restrict__ AuLo,
    int is_first, int is_final)
{
    int t = blockIdx.x, b = blockIdx.y;
    int tid = threadIdx.x;
    size_t ro = (size_t)(b * LSEQ + t) * DI;
    const float* yr = yraw + ro;
    float* yp = ybuf + ro;

    float s = 0.f, s2 = 0.f;
    float vloc[DI / 256];
    #pragma unroll
    for (int i = 0; i < DI / 256; ++i) {
        float v = yr[tid + i * 256];
        vloc[i] = v; s += v; s2 += v * v;
    }
    #pragma unroll
    for (int off = 32; off >= 1; off >>= 1) {
        s += __shfl_down(s, off, 64);
        s2 += __shfl_down(s2, off, 64);
    }
    __shared__ float rs[4], rs2[4];
    __shared__ float smean, srstd;
    int wid = tid >> 6, lane = tid & 63;
    if (lane == 0) { rs[wid] = s; rs2[wid] = s2; }
    __syncthreads();
    if (tid == 0) {
        float S = rs[0] + rs[1] + rs[2] + rs[3];
        float S2 = rs2[0] + rs2[1] + rs2[2] + rs2[3];
        float m = S / (float)DI;
        float var = S2 / (float)DI - m * m;
        smean = m;
        srstd = rsqrtf(var + EPSF);
    }
    __syncthreads();
    float m = smean, r = srstd;

    #pragma unroll
    for (int i = 0; i < DI / 256; ++i) {
        int idx = tid + i * 256;
        float ln = (vloc[i] - m) * r * gamma[idx] + beta[idx];
        float ypv = is_first ? 0.f : yp[idx];
        float yn = is_final ? ln : fmaf(STEPF, ln - ypv, ypv);
        yp[idx] = yn;
        if (!is_final) {
            float xv = bf2f(XHi[ro + idx]) + bf2f(XLo[ro + idx]);
            ushort_t h, l;
            split1(xv - yn, h, l);
            AuHi[ro + idx] = h;
            AuLo[ro + idx] = l;
        }
    }
}

__global__ __launch_bounds__(256) void bc_init(
    const float* __restrict__ xdbl, float* __restrict__ Btb, float* __restrict__ Ctb)
{
    int tok = blockIdx.x * 8 + (threadIdx.x >> 5);
    int i = threadIdx.x & 31;
    float v = xdbl[(size_t)tok * XDBL_N + DTR + i];
    float sq = v * v;
    #pragma unroll
    for (int off = 8; off >= 1; off >>= 1) sq += __shfl_xor(sq, off, 16);
    float nrm = fmaxf(sqrtf(sq), EPSF);
    float outv = v / nrm;
    if (i < 16) Btb[(size_t)tok * NST + i] = outv;
    else        Ctb[(size_t)tok * NST + (i - 16)] = outv;
}

__global__ __launch_bounds__(256) void fill_zero(float* p, size_t n)
{
    size_t i = (size_t)blockIdx.x * blockDim.x + threadIdx.x;
    size_t stride = (size_t)gridDim.x * blockDim.x;
    for (; i < n; i += stride) p[i] = 0.f;
}

// ---------------------------------------------------------------------------
extern "C" void kernel_launch(void* const* d_in, const int* in_sizes, int n_in,
                              void* d_out, int out_size, void* d_ws, size_t ws_size,
                              hipStream_t stream)
{
    const float* hs    = (const float*)d_in[0];
    const float* W_in  = (const float*)d_in[1];
    const float* W_x   = (const float*)d_in[2];
    const float* W_dt  = (const float*)d_in[3];
    const float* b_dt  = (const float*)d_in[4];
    const float* A_log = (const float*)d_in[5];
    const float* W_bc  = (const float*)d_in[6];
    const float* W_zy  = (const float*)d_in[7];
    const float* W_mix = (const float*)d_in[8];
    const float* Dp    = (const float*)d_in[9];
    const float* g_ln  = (const float*)d_in[10];
    const float* b_ln  = (const float*)d_in[11];
    const float* W_out = (const float*)d_in[12];
    float* out = (float*)d_out;

    char* ws = (char*)d_ws;
    size_t off = 0;
    auto alloc = [&](size_t bytes) {
        void* p = (void*)(ws + off);
        off += (bytes + 255) & ~(size_t)255;
        return p;
    };
    float*    z      = (float*)alloc((size_t)NTOK * DI * 4);       // 32 MB
    ushort_t* XHi    = (ushort_t*)alloc((size_t)NTOK * DI * 2);    // 16 MB (epilogue: shift1(y) hi)
    ushort_t* XLo    = (ushort_t*)alloc((size_t)NTOK * DI * 2);    // 16 MB
    float*    delta  = (float*)alloc((size_t)NTOK * DI * 4);       // 32 MB (epilogue: Ghi|Glo)
    float*    ubuf   = (float*)alloc((size_t)NTOK * DI * 4);       // 32 MB (prologue: hs/Win splits)
    float*    yA     = (float*)alloc((size_t)NTOK * DI * 4);       // 32 MB (prologue: Pd + Xd splits)
    ushort_t* AuHi   = (ushort_t*)alloc((size_t)NTOK * DI * 2);    // 16 MB (prologue: Wx split)
    ushort_t* AuLo   = (ushort_t*)alloc((size_t)NTOK * DI * 2);    // 16 MB (prologue: Wdt split)
    ushort_t* WextHi = (ushort_t*)alloc((size_t)NEXT * DI * 2);    // 8.5 MB (epilogue: Wzy hi)
    ushort_t* WextLo = (ushort_t*)alloc((size_t)NEXT * DI * 2);    // 8.5 MB (epilogue: Wzy lo)
    float*    Ac     = (float*)alloc((size_t)B_SZ * NCH * DI * NST * 4); // 8 MB (epilogue: Wout hi)
    float*    Hend   = (float*)alloc((size_t)B_SZ * NCH * DI * NST * 4); // 8 MB (epilogue: Wout lo)
    float*    xdbl   = (float*)alloc((size_t)NTOK * XDBL_N * 4);   // 1.5 MB
    float*    Btb    = (float*)alloc((size_t)NTOK * NST * 4);
    float*    Ctb    = (float*)alloc((size_t)NTOK * NST * 4);
    float*    Pbuf   = (float*)alloc((size_t)NTOK * 32 * 4);       // 0.5 MB
    float*    xWbc   = (float*)alloc((size_t)NTOK * 128 * 4);      // 2 MB

    // prologue aliases
    ushort_t* HsHi  = (ushort_t*)ubuf;
    ushort_t* HsLo  = HsHi + (size_t)NTOK * DM;
    ushort_t* WinHi = HsLo + (size_t)NTOK * DM;
    ushort_t* WinLo = WinHi + (size_t)(2 * DI) * DM;               // = 32 MB exactly
    float*    Pd    = yA;                                          // 8 x 4096 x 128 = 16 MB
    ushort_t* XdHi  = (ushort_t*)(yA + (size_t)NTOK * DI / 2);     // yA + 16 MB
    ushort_t* XdLo  = XdHi + (size_t)NTOK * DTR;
    ushort_t* WxHi  = AuHi;                                        // 128 x 2048 bf16
    ushort_t* WxLo  = WxHi + (size_t)128 * DI;
    ushort_t* WdtHi = AuLo;                                        // 2048 x 64 bf16
    ushort_t* WdtLo = WdtHi + (size_t)DI * DTR;
    // epilogue aliases
    ushort_t* Ghi   = (ushort_t*)delta;
    ushort_t* Glo   = Ghi + (size_t)NTOK * DI;
    ushort_t* WzyHi = WextHi;
    ushort_t* WzyLo = WextLo;
    ushort_t* WoutHi= (ushort_t*)Ac;
    ushort_t* WoutLo= (ushort_t*)Hend;
    float*    yraw  = ubuf;

    dim3 blk(256);

    // --- prologue: splits ---
    split_bf16<0><<<4096, blk, 0, stream>>>(hs, HsHi, HsLo, NTOK, DM, DM);
    split_bf16<0><<<4096, blk, 0, stream>>>(W_in, WinHi, WinLo, 2 * DI, DM, DM);
    fill_zero<<<64, blk, 0, stream>>>((float*)WxHi, (size_t)128 * DI / 2);
    fill_zero<<<64, blk, 0, stream>>>((float*)WxLo, (size_t)128 * DI / 2);
    split_bf16<0><<<512, blk, 0, stream>>>(W_x, WxHi, WxLo, XDBL_N, DI, DI);
    split_bf16<0><<<128, blk, 0, stream>>>(W_dt, WdtHi, WdtLo, DI, DTR, DTR);
    // Wext = [W_mix rows 0..2047 | W_bc rows 2048..2079 | zeros 2080..2175]
    split_bf16<0><<<4096, blk, 0, stream>>>(W_mix, WextHi, WextLo, DI, DI, DI);
    fill_zero<<<128, blk, 0, stream>>>((float*)(WextHi + (size_t)DI * DI), (size_t)128 * DI / 2);
    fill_zero<<<128, blk, 0, stream>>>((float*)(WextLo + (size_t)DI * DI), (size_t)128 * DI / 2);
    split_bf16<0><<<64, blk, 0, stream>>>(W_bc, WextHi + (size_t)DI * DI,
                                          WextLo + (size_t)DI * DI, 32, DI, DI);

    // x = hs @ W_in[:DI]^T (split out), z = hs @ W_in[DI:]^T (fp32)
    mfma_gemm<4, 1><<<dim3(DI / 128, NTOK / 128), blk, 0, stream>>>(
        HsHi, HsLo, WinHi, WinLo, nullptr, nullptr, nullptr, XHi, XLo,
        nullptr, 0, NTOK, DI, DM, 0, 0, DI);
    mfma_gemm<0, 1><<<dim3(DI / 128, NTOK / 128), blk, 0, stream>>>(
        HsHi, HsLo, WinHi + (size_t)DI * DM, WinLo + (size_t)DI * DM,
        nullptr, nullptr, z, nullptr, nullptr, nullptr, 0, NTOK, DI, DM, 0, 0, DI);

    // xdbl: split-K (8) over K=DI, N padded to 128
    mfma_gemm<0, 1><<<dim3(1, NTOK / 128, 8), blk, 0, stream>>>(
        XHi, XLo, WxHi, WxLo, nullptr, nullptr, Pd, nullptr, nullptr,
        nullptr, 0, NTOK, 128, DI, 0, 0, 128);
    reduce_xdbl<<<(NTOK * XDBL_N + 255) / 256, blk, 0, stream>>>(Pd, xdbl);

    // delta = softplus(dt_low @ W_dt^T + b_dt)
    split_bf16<0><<<256, blk, 0, stream>>>(xdbl, XdHi, XdLo, NTOK, DTR, XDBL_N);
    mfma_gemm<2, 1><<<dim3(DI / 128, NTOK / 128), blk, 0, stream>>>(
        XdHi, XdLo, WdtHi, WdtLo, nullptr, b_dt, delta, nullptr, nullptr,
        nullptr, 0, NTOK, DI, DTR, 0, 0, DI);

    bc_init<<<NTOK / 8, 256, 0, stream>>>(xdbl, Btb, Ctb);

    // xWbc = x @ Wext[2048:2176]^T  (once; cols 0..31 = x @ W_bc^T)
    mfma_gemm<0, 1><<<dim3(1, NTOK / 128), blk, 0, stream>>>(
        XHi, XLo, WextHi + (size_t)DI * DI, WextLo + (size_t)DI * DI,
        nullptr, nullptr, xWbc, nullptr, nullptr, nullptr, 0,
        NTOK, 128, DI, 0, 0, 128);

    // --- fixed-point loop ---
    for (int it = 0; it <= FP_ITERS; ++it) {
        const ushort_t* Ah = (it == 0) ? XHi : AuHi;
        const ushort_t* Al = (it == 0) ? XLo : AuLo;
        const float* Ey = (it == 0) ? nullptr : yA;
        if (it <= 3) {
            mfma_gemm<5, 0><<<dim3(NEXT / 128, NTOK / 128), blk, 0, stream>>>(
                Ah, Al, WextHi, WextLo, Ey, nullptr, ubuf, nullptr, nullptr,
                Pbuf, DI, NTOK, NEXT, DI, DI, 0, DI);
        } else {
            mfma_gemm<5, 1><<<dim3(NEXT / 128, NTOK / 128), blk, 0, stream>>>(
                Ah, Al, WextHi, WextLo, Ey, nullptr, ubuf, nullptr, nullptr,
                Pbuf, DI, NTOK, NEXT, DI, DI, 0, DI);
        }
        bc_make<<<NTOK / 8, blk, 0, stream>>>(xdbl, xWbc, Pbuf, Btb, Ctb);
        scan_pass1<<<dim3(DI / 256, NCH, B_SZ), blk, 0, stream>>>(
            delta, ubuf, Btb, A_log, Ac, Hend);
        scan_pass2<<<dim3(B_SZ * DI * NST / 256), blk, 0, stream>>>(Ac, Hend);
        scan_pass3<<<dim3(DI / 256, NCH, B_SZ), blk, 0, stream>>>(
            delta, ubuf, Btb, Ctb, A_log, Dp, Ac, yraw);
        ln_update<<<dim3(LSEQ, B_SZ), blk, 0, stream>>>(
            yraw, yA, g_ln, b_ln, XHi, XLo, AuHi, AuLo,
            it == 0 ? 1 : 0, it == FP_ITERS ? 1 : 0);
    }

    // --- epilogue ---
    // g = silu(z + shift1(y) @ W_zy^T) * y   (split into delta buf)
    split_bf16<2><<<8192, blk, 0, stream>>>(yA, XHi, XLo, NTOK, DI, DI);
    split_bf16<0><<<4096, blk, 0, stream>>>(W_zy, WzyHi, WzyLo, DI, DI, DI);
    mfma_gemm<3, 1><<<dim3(DI / 128, NTOK / 128), blk, 0, stream>>>(
        XHi, XLo, WzyHi, WzyLo, z, yA, nullptr, Ghi, Glo, nullptr, 0,
        NTOK, DI, DI, DI, DI, DI);

    // out = g @ W_out^T
    split_bf16<0><<<2048, blk, 0, stream>>>(W_out, WoutHi, WoutLo, DM, DI, DI);
    mfma_gemm<0, 1><<<dim3(DM / 128, NTOK / 128), blk, 0, stream>>>(
        Ghi, Glo, WoutHi, WoutLo, nullptr, nullptr, out, nullptr, nullptr,
        nullptr, 0, NTOK, DM, DI, 0, 0, DM);
}

// Round 6
// 2698.051 us; speedup vs baseline: 1.2872x; 1.0873x over previous
//
#include <hip/hip_runtime.h>
#include <math.h>

#define B_SZ   2
#define LSEQ   2048
#define DM     1024
#define DI     2048
#define NST    16
#define DTR    64
#define XDBL_N 96
#define NTOK   (B_SZ * LSEQ)
#define NCH    32
#define CS     64
#define EPSF   1e-5f
#define STEPF  0.99f
#define FP_ITERS 8
#define PKZ    4      // split-K factor for the skinny P-GEMM

typedef __attribute__((ext_vector_type(8))) short bf16x8;
typedef __attribute__((ext_vector_type(4))) float f32x4;
typedef unsigned short ushort_t;

__device__ __forceinline__ ushort_t f2bf(float v) {
    unsigned u = __float_as_uint(v);
    unsigned r = (u + 0x7fffu + ((u >> 16) & 1u)) >> 16;   // RNE
    return (ushort_t)r;
}
__device__ __forceinline__ float bf2f(ushort_t h) {
    return __uint_as_float(((unsigned)h) << 16);
}
__device__ __forceinline__ void split1(float v, ushort_t& h, ushort_t& l) {
    h = f2bf(v);
    l = f2bf(v - bf2f(h));
}
__device__ __forceinline__ void load_lds16(const void* g, void* l) {
    __builtin_amdgcn_global_load_lds(
        (const __attribute__((address_space(1))) unsigned int*)g,
        (__attribute__((address_space(3))) unsigned int*)l, 16, 0, 0);
}

// ---------------------------------------------------------------------------
// Split fp32 -> bf16 hi/lo pair.
// MODE 0: A plain      (lda)
// MODE 2: shift1(A)    (row t reads t-1 within each LSEQ batch)
// ---------------------------------------------------------------------------
template <int MODE>
__global__ __launch_bounds__(256) void split_bf16(
    const float* __restrict__ A,
    ushort_t* __restrict__ Hi, ushort_t* __restrict__ Lo,
    int M, int K, int lda)
{
    int K4 = K >> 2;
    long total = (long)M * K4;
    for (long i = (long)blockIdx.x * 256 + threadIdx.x; i < total;
         i += (long)gridDim.x * 256) {
        int m = (int)(i / K4);
        int k = (int)(i - (long)m * K4) * 4;
        float4 a;
        if (MODE == 2) {
            int t = m & (LSEQ - 1);
            if (t == 0) a = make_float4(0.f, 0.f, 0.f, 0.f);
            else        a = *(const float4*)(A + (size_t)(m - 1) * lda + k);
        } else {
            a = *(const float4*)(A + (size_t)m * lda + k);
        }
        ushort4 hv, lv;
        split1(a.x, hv.x, lv.x);
        split1(a.y, hv.y, lv.y);
        split1(a.z, hv.z, lv.z);
        split1(a.w, hv.w, lv.w);
        *(ushort4*)(Hi + (size_t)m * K + k) = hv;
        *(ushort4*)(Lo + (size_t)m * K + k) = lv;
    }
}

// ---------------------------------------------------------------------------
// Split-bf16 MFMA GEMM, 128x128 tile, BK=32, 256 threads = 4 waves (2x2 of
// 64x64). PROD3: 3 products (hh,hl,lh) vs 2 (hh,hl). Split-K via gridDim.z.
// Grid (N/128, M/128[, splitk]) — keep x-dim a power of 2: the 544-block
// N=2176 fusion (round 4/5) broke L2 streaming locality (FETCH 172->254 MB).
// EOP: 0 C = acc
//      1 C = acc + E[m][n]                        (ldE)
//      2 C = softplus(acc + E2[n])                (bias vector)
//      3 g = silu(E[m][n]+acc) * E2[m][n]; split -> Chi/Clo
//      4 split(acc) -> Chi/Clo
// ---------------------------------------------------------------------------
template <int EOP, int PROD3>
__global__ __launch_bounds__(256) void mfma_gemm(
    const ushort_t* __restrict__ Ahi, const ushort_t* __restrict__ Alo,
    const ushort_t* __restrict__ Whi, const ushort_t* __restrict__ Wlo,
    const float* __restrict__ E, const float* __restrict__ E2,
    float* __restrict__ C, ushort_t* __restrict__ Chi, ushort_t* __restrict__ Clo,
    int M, int N, int K, int ldE, int ldE2, int ldc)
{
    __shared__ __align__(16) short lds[16384];  // 32 KB: Ahi|Alo|Whi|Wlo, each 128x32
    short* sAhi = lds;
    short* sAlo = lds + 4096;
    short* sWhi = lds + 8192;
    short* sWlo = lds + 12288;
    char* ldsc = (char*)lds;

    const int tid = threadIdx.x, lane = tid & 63, w = tid >> 6;
    const int m0 = blockIdx.y * 128, n0 = blockIdx.x * 128;
    const int wm = (w & 1) * 64, wn = (w >> 1) * 64;

    const int ksub = K / gridDim.z;
    const int kbeg = blockIdx.z * ksub;
    if (gridDim.z > 1) C += (size_t)blockIdx.z * M * ldc;

    f32x4 zero4 = {0.f, 0.f, 0.f, 0.f};
    f32x4 acc[4][4];
    #pragma unroll
    for (int mi = 0; mi < 4; ++mi)
        #pragma unroll
        for (int ni = 0; ni < 4; ++ni) acc[mi][ni] = zero4;

    size_t aoff[2], woff[2];
    #pragma unroll
    for (int i = 0; i < 2; ++i) {
        int j = w * 2 + i;
        int row = j * 16 + (lane >> 2);
        int ke = (lane & 3) * 8;
        aoff[i] = (size_t)(m0 + row) * K + kbeg + ke;
        woff[i] = (size_t)(n0 + row) * K + kbeg + ke;
    }
    const int abase = (wm + (lane & 15)) * 32 + (lane >> 4) * 8;
    const int bbase = (wn + (lane & 15)) * 32 + (lane >> 4) * 8;

    for (int k0 = 0; k0 < ksub; k0 += 32) {
        #pragma unroll
        for (int i = 0; i < 2; ++i) {
            int dst = (w * 2 + i) * 1024;
            load_lds16(Ahi + aoff[i], ldsc + dst);
            load_lds16(Alo + aoff[i], ldsc + 8192 + dst);
            load_lds16(Whi + woff[i], ldsc + 16384 + dst);
            load_lds16(Wlo + woff[i], ldsc + 24576 + dst);
            aoff[i] += 32; woff[i] += 32;
        }
        __syncthreads();

        bf16x8 ah[4], al[4], bh[4], bl[4];
        #pragma unroll
        for (int mi = 0; mi < 4; ++mi) {
            ah[mi] = *(const bf16x8*)(sAhi + abase + mi * 512);
            al[mi] = *(const bf16x8*)(sAlo + abase + mi * 512);
        }
        #pragma unroll
        for (int ni = 0; ni < 4; ++ni) {
            bh[ni] = *(const bf16x8*)(sWhi + bbase + ni * 512);
            bl[ni] = *(const bf16x8*)(sWlo + bbase + ni * 512);
        }
        #pragma unroll
        for (int mi = 0; mi < 4; ++mi)
            #pragma unroll
            for (int ni = 0; ni < 4; ++ni) {
                acc[mi][ni] = __builtin_amdgcn_mfma_f32_16x16x32_bf16(ah[mi], bh[ni], acc[mi][ni], 0, 0, 0);
                acc[mi][ni] = __builtin_amdgcn_mfma_f32_16x16x32_bf16(ah[mi], bl[ni], acc[mi][ni], 0, 0, 0);
                if (PROD3)
                    acc[mi][ni] = __builtin_amdgcn_mfma_f32_16x16x32_bf16(al[mi], bh[ni], acc[mi][ni], 0, 0, 0);
            }
        __syncthreads();
    }

    // C/D layout: col = lane&15, row = (lane>>4)*4 + reg
    const int col = lane & 15, rb = (lane >> 4) * 4;
    #pragma unroll
    for (int mi = 0; mi < 4; ++mi) {
        #pragma unroll
        for (int r = 0; r < 4; ++r) {
            int gm = m0 + wm + mi * 16 + rb + r;
            #pragma unroll
            for (int ni = 0; ni < 4; ++ni) {
                int gn = n0 + wn + ni * 16 + col;
                float v = acc[mi][ni][r];
                if (EOP == 0) {
                    C[(size_t)gm * ldc + gn] = v;
                } else if (EOP == 1) {
                    C[(size_t)gm * ldc + gn] = v + E[(size_t)gm * ldE + gn];
                } else if (EOP == 2) {
                    v += E2[gn];
                    v = (v > 20.f) ? v : log1pf(expf(v));
                    C[(size_t)gm * ldc + gn] = v;
                } else if (EOP == 3) {
                    float z2 = E[(size_t)gm * ldE + gn] + v;
                    float s = 1.f / (1.f + __expf(-z2));
                    float g = z2 * s * E2[(size_t)gm * ldE2 + gn];
                    ushort_t h, l;
                    split1(g, h, l);
                    Chi[(size_t)gm * ldc + gn] = h;
                    Clo[(size_t)gm * ldc + gn] = l;
                } else {  // EOP == 4
                    ushort_t h, l;
                    split1(v, h, l);
                    Chi[(size_t)gm * ldc + gn] = h;
                    Clo[(size_t)gm * ldc + gn] = l;
                }
            }
        }
    }
}

// xdbl[m][n] = sum_z Pd[z][m][128+n], n < 96
__global__ __launch_bounds__(256) void reduce_xdbl(
    const float* __restrict__ Pd, float* __restrict__ xdbl)
{
    int idx = blockIdx.x * 256 + threadIdx.x;
    if (idx >= NTOK * XDBL_N) return;
    int m = idx / XDBL_N, n = idx - m * XDBL_N;
    float s = 0.f;
    #pragma unroll
    for (int zz = 0; zz < 8; ++zz)
        s += Pd[(size_t)zz * NTOK * 128 + (size_t)m * 128 + n];
    xdbl[(size_t)m * XDBL_N + n] = s;
}

// ---------------------------------------------------------------------------
// Bt/Ct[t+1] = normalize(B0C0[t+1] + xWbc[t] - sum_z Pp[z][t])
// ---------------------------------------------------------------------------
__global__ __launch_bounds__(256) void bc_make(
    const float* __restrict__ xdbl, const float* __restrict__ xWbc,
    const float* __restrict__ Pp, float* __restrict__ Btb, float* __restrict__ Ctb)
{
    int tok = blockIdx.x * 8 + (threadIdx.x >> 5);
    int j = threadIdx.x & 31;
    int t = tok & (LSEQ - 1);
    if (t == LSEQ - 1) return;
    int tn = tok + 1;
    float p = 0.f;
    #pragma unroll
    for (int zz = 0; zz < PKZ; ++zz)
        p += Pp[(size_t)zz * NTOK * 128 + (size_t)tok * 128 + j];
    float v = xdbl[(size_t)tn * XDBL_N + DTR + j]
            + xWbc[(size_t)tok * 128 + j] - p;
    float sq = v * v;
    #pragma unroll
    for (int off = 8; off >= 1; off >>= 1) sq += __shfl_xor(sq, off, 16);
    float nrm = fmaxf(sqrtf(sq), EPSF);
    float outv = v / nrm;
    if (j < 16) Btb[(size_t)tn * NST + j] = outv;
    else        Ctb[(size_t)tn * NST + (j - 16)] = outv;
}

// ---------------------------------------------------------------------------
// Chunked selective scan.
// ---------------------------------------------------------------------------
__global__ __launch_bounds__(256) void scan_pass1(
    const float* __restrict__ delta, const float* __restrict__ u,
    const float* __restrict__ Bt, const float* __restrict__ Alog,
    float* __restrict__ Ac, float* __restrict__ Hend)
{
    int d = blockIdx.x * 256 + threadIdx.x;
    int c = blockIdx.y, b = blockIdx.z;
    int t0 = c * CS;
    __shared__ float sB[CS][NST];
    for (int i = threadIdx.x; i < CS * NST; i += 256)
        ((float*)sB)[i] = Bt[(size_t)(b * LSEQ + t0) * NST + i];
    __syncthreads();

    float Avals[NST];
    #pragma unroll
    for (int n = 0; n < NST; ++n) Avals[n] = -__expf(Alog[d * NST + n]);
    float h[NST] = {};
    float Pp[NST];
    #pragma unroll
    for (int n = 0; n < NST; ++n) Pp[n] = 1.f;

    const float* dptr = delta + (size_t)(b * LSEQ + t0) * DI + d;
    const float* uptr = u + (size_t)(b * LSEQ + t0) * DI + d;
    for (int tt = 0; tt < CS; ++tt) {
        float dt = dptr[(size_t)tt * DI];
        float ut = uptr[(size_t)tt * DI];
        float wv = dt * ut;
        #pragma unroll
        for (int n = 0; n < NST; ++n) {
            float a = __expf(dt * Avals[n]);
            Pp[n] *= a;
            h[n] = fmaf(a, h[n], wv * sB[tt][n]);
        }
    }
    size_t o = ((size_t)((b * NCH + c) * DI) + d) * NST;
    #pragma unroll
    for (int n = 0; n < NST; ++n) { Ac[o + n] = Pp[n]; Hend[o + n] = h[n]; }
}

__global__ __launch_bounds__(256) void scan_pass2(
    float* __restrict__ Ac, const float* __restrict__ Hend)
{
    int idx = blockIdx.x * 256 + threadIdx.x;
    int b = idx / (DI * NST);
    int dn = idx % (DI * NST);
    float h = 0.f;
    for (int c = 0; c < NCH; ++c) {
        size_t o = (size_t)(b * NCH + c) * DI * NST + dn;
        float a = Ac[o];
        float e = Hend[o];
        Ac[o] = h;               // Hin in place
        h = fmaf(a, h, e);
    }
}

__global__ __launch_bounds__(256) void scan_pass3(
    const float* __restrict__ delta, const float* u,
    const float* __restrict__ Bt, const float* __restrict__ Ct,
    const float* __restrict__ Alog, const float* __restrict__ Dp,
    const float* __restrict__ Hin, float* yraw)  // yraw may alias u
{
    int d = blockIdx.x * 256 + threadIdx.x;
    int c = blockIdx.y, b = blockIdx.z;
    int t0 = c * CS;
    __shared__ float sB[CS][NST];
    __shared__ float sC[CS][NST];
    for (int i = threadIdx.x; i < CS * NST; i += 256) {
        ((float*)sB)[i] = Bt[(size_t)(b * LSEQ + t0) * NST + i];
        ((float*)sC)[i] = Ct[(size_t)(b * LSEQ + t0) * NST + i];
    }
    __syncthreads();

    float Avals[NST];
    #pragma unroll
    for (int n = 0; n < NST; ++n) Avals[n] = -__expf(Alog[d * NST + n]);
    float h[NST];
    size_t o = ((size_t)((b * NCH + c) * DI) + d) * NST;
    #pragma unroll
    for (int n = 0; n < NST; ++n) h[n] = Hin[o + n];
    float Dd = Dp[d];

    const float* dptr = delta + (size_t)(b * LSEQ + t0) * DI + d;
    const float* uptr = u + (size_t)(b * LSEQ + t0) * DI + d;
    float* yptr = yraw + (size_t)(b * LSEQ + t0) * DI + d;
    for (int tt = 0; tt < CS; ++tt) {
        float dt = dptr[(size_t)tt * DI];
        float ut = uptr[(size_t)tt * DI];
        float wv = dt * ut;
        float acc = 0.f;
        #pragma unroll
        for (int n = 0; n < NST; ++n) {
            float a = __expf(dt * Avals[n]);
            h[n] = fmaf(a, h[n], wv * sB[tt][n]);
            acc = fmaf(h[n], sC[tt][n], acc);
        }
        yptr[(size_t)tt * DI] = fmaf(Dd, ut, acc);
    }
}

// ---------------------------------------------------------------------------
// Per-token LN -> fp update (in place) -> split(x - y_next) for next u-GEMM.
// ---------------------------------------------------------------------------
__global__ __launch_bounds__(256) void ln_update(
    const float* __restrict__ yraw, float* __restrict__ ybuf,
    const float* __restrict__ gamma, const float* __restrict__ beta,
    const ushort_t* __restrict__ XHi, const ushort_t* __restrict__ XLo,
    ushort_t* __restrict__ AuHi, ushort_t* __restrict__ AuLo,
    int is_first, int is_final)
{
    int t = blockIdx.x, b = blockIdx.y;
    int tid = threadIdx.x;
    size_t ro = (size_t)(b * LSEQ + t) * DI;
    const float* yr = yraw + ro;
    float* yp = ybuf + ro;

    float s = 0.f, s2 = 0.f;
    float vloc[DI / 256];
    #pragma unroll
    for (int i = 0; i < DI / 256; ++i) {
        float v = yr[tid + i * 256];
        vloc[i] = v; s += v; s2 += v * v;
    }
    #pragma unroll
    for (int off = 32; off >= 1; off >>= 1) {
        s += __shfl_down(s, off, 64);
        s2 += __shfl_down(s2, off, 64);
    }
    __shared__ float rs[4], rs2[4];
    __shared__ float smean, srstd;
    int wid = tid >> 6, lane = tid & 63;
    if (lane == 0) { rs[wid] = s; rs2[wid] = s2; }
    __syncthreads();
    if (tid == 0) {
        float S = rs[0] + rs[1] + rs[2] + rs[3];
        float S2 = rs2[0] + rs2[1] + rs2[2] + rs2[3];
        float m = S / (float)DI;
        float var = S2 / (float)DI - m * m;
        smean = m;
        srstd = rsqrtf(var + EPSF);
    }
    __syncthreads();
    float m = smean, r = srstd;

    #pragma unroll
    for (int i = 0; i < DI / 256; ++i) {
        int idx = tid + i * 256;
        float ln = (vloc[i] - m) * r * gamma[idx] + beta[idx];
        float ypv = is_first ? 0.f : yp[idx];
        float yn = is_final ? ln : fmaf(STEPF, ln - ypv, ypv);
        yp[idx] = yn;
        if (!is_final) {
            float xv = bf2f(XHi[ro + idx]) + bf2f(XLo[ro + idx]);
            ushort_t h, l;
            split1(xv - yn, h, l);
            AuHi[ro + idx] = h;
            AuLo[ro + idx] = l;
        }
    }
}

__global__ __launch_bounds__(256) void bc_init(
    const float* __restrict__ xdbl, float* __restrict__ Btb, float* __restrict__ Ctb)
{
    int tok = blockIdx.x * 8 + (threadIdx.x >> 5);
    int i = threadIdx.x & 31;
    float v = xdbl[(size_t)tok * XDBL_N + DTR + i];
    float sq = v * v;
    #pragma unroll
    for (int off = 8; off >= 1; off >>= 1) sq += __shfl_xor(sq, off, 16);
    float nrm = fmaxf(sqrtf(sq), EPSF);
    float outv = v / nrm;
    if (i < 16) Btb[(size_t)tok * NST + i] = outv;
    else        Ctb[(size_t)tok * NST + (i - 16)] = outv;
}

__global__ __launch_bounds__(256) void fill_zero(float* p, size_t n)
{
    size_t i = (size_t)blockIdx.x * blockDim.x + threadIdx.x;
    size_t stride = (size_t)gridDim.x * blockDim.x;
    for (; i < n; i += stride) p[i] = 0.f;
}

// ---------------------------------------------------------------------------
extern "C" void kernel_launch(void* const* d_in, const int* in_sizes, int n_in,
                              void* d_out, int out_size, void* d_ws, size_t ws_size,
                              hipStream_t stream)
{
    const float* hs    = (const float*)d_in[0];
    const float* W_in  = (const float*)d_in[1];
    const float* W_x   = (const float*)d_in[2];
    const float* W_dt  = (const float*)d_in[3];
    const float* b_dt  = (const float*)d_in[4];
    const float* A_log = (const float*)d_in[5];
    const float* W_bc  = (const float*)d_in[6];
    const float* W_zy  = (const float*)d_in[7];
    const float* W_mix = (const float*)d_in[8];
    const float* Dp    = (const float*)d_in[9];
    const float* g_ln  = (const float*)d_in[10];
    const float* b_ln  = (const float*)d_in[11];
    const float* W_out = (const float*)d_in[12];
    float* out = (float*)d_out;

    char* ws = (char*)d_ws;
    size_t off = 0;
    auto alloc = [&](size_t bytes) {
        void* p = (void*)(ws + off);
        off += (bytes + 255) & ~(size_t)255;
        return p;
    };
    float*    z      = (float*)alloc((size_t)NTOK * DI * 4);       // 32 MB
    ushort_t* XHi    = (ushort_t*)alloc((size_t)NTOK * DI * 2);    // 16 MB (epilogue: shift1(y) hi)
    ushort_t* XLo    = (ushort_t*)alloc((size_t)NTOK * DI * 2);    // 16 MB
    float*    delta  = (float*)alloc((size_t)NTOK * DI * 4);       // 32 MB (epilogue: Ghi|Glo)
    float*    ubuf   = (float*)alloc((size_t)NTOK * DI * 4);       // 32 MB (prologue: hs/Win splits)
    float*    yA     = (float*)alloc((size_t)NTOK * DI * 4);       // 32 MB (prologue: Pd + Xd splits)
    ushort_t* AuHi   = (ushort_t*)alloc((size_t)NTOK * DI * 2);    // 16 MB (prologue: Wx split)
    ushort_t* AuLo   = (ushort_t*)alloc((size_t)NTOK * DI * 2);    // 16 MB (prologue: Wdt split)
    ushort_t* WmixHi = (ushort_t*)alloc((size_t)DI * DI * 2);      // 8 MB (epilogue: Wzy hi)
    ushort_t* WmixLo = (ushort_t*)alloc((size_t)DI * DI * 2);      // 8 MB (epilogue: Wzy lo)
    float*    Ac     = (float*)alloc((size_t)B_SZ * NCH * DI * NST * 4); // 8 MB (epilogue: Wout hi)
    float*    Hend   = (float*)alloc((size_t)B_SZ * NCH * DI * NST * 4); // 8 MB (epilogue: Wout lo)
    float*    xdbl   = (float*)alloc((size_t)NTOK * XDBL_N * 4);   // 1.5 MB
    float*    Btb    = (float*)alloc((size_t)NTOK * NST * 4);
    float*    Ctb    = (float*)alloc((size_t)NTOK * NST * 4);
    float*    Pp     = (float*)alloc((size_t)PKZ * NTOK * 128 * 4);// 8 MB (P partials)
    float*    xWbc   = (float*)alloc((size_t)NTOK * 128 * 4);      // 2 MB
    ushort_t* WbcHi  = (ushort_t*)alloc((size_t)128 * DI * 2);     // 0.5 MB (128 rows: 32 real + 96 zero)
    ushort_t* WbcLo  = (ushort_t*)alloc((size_t)128 * DI * 2);     // 0.5 MB

    // prologue aliases
    ushort_t* HsHi  = (ushort_t*)ubuf;
    ushort_t* HsLo  = HsHi + (size_t)NTOK * DM;
    ushort_t* WinHi = HsLo + (size_t)NTOK * DM;
    ushort_t* WinLo = WinHi + (size_t)(2 * DI) * DM;               // = 32 MB exactly
    float*    Pd    = yA;                                          // 8 x 4096 x 128 = 16 MB
    ushort_t* XdHi  = (ushort_t*)(yA + (size_t)NTOK * DI / 2);     // yA + 16 MB
    ushort_t* XdLo  = XdHi + (size_t)NTOK * DTR;
    ushort_t* WxHi  = AuHi;                                        // 128 x 2048 bf16
    ushort_t* WxLo  = WxHi + (size_t)128 * DI;
    ushort_t* WdtHi = AuLo;                                        // 2048 x 64 bf16
    ushort_t* WdtLo = WdtHi + (size_t)DI * DTR;
    // epilogue aliases
    ushort_t* Ghi   = (ushort_t*)delta;
    ushort_t* Glo   = Ghi + (size_t)NTOK * DI;
    ushort_t* WzyHi = WmixHi;
    ushort_t* WzyLo = WmixLo;
    ushort_t* WoutHi= (ushort_t*)Ac;
    ushort_t* WoutLo= (ushort_t*)Hend;
    float*    yraw  = ubuf;

    dim3 blk(256);

    // --- prologue: splits ---
    split_bf16<0><<<4096, blk, 0, stream>>>(hs, HsHi, HsLo, NTOK, DM, DM);
    split_bf16<0><<<4096, blk, 0, stream>>>(W_in, WinHi, WinLo, 2 * DI, DM, DM);
    fill_zero<<<64, blk, 0, stream>>>((float*)WxHi, (size_t)128 * DI / 2);
    fill_zero<<<64, blk, 0, stream>>>((float*)WxLo, (size_t)128 * DI / 2);
    split_bf16<0><<<512, blk, 0, stream>>>(W_x, WxHi, WxLo, XDBL_N, DI, DI);
    split_bf16<0><<<128, blk, 0, stream>>>(W_dt, WdtHi, WdtLo, DI, DTR, DTR);
    split_bf16<0><<<4096, blk, 0, stream>>>(W_mix, WmixHi, WmixLo, DI, DI, DI);
    fill_zero<<<128, blk, 0, stream>>>((float*)WbcHi, (size_t)128 * DI / 2);
    fill_zero<<<128, blk, 0, stream>>>((float*)WbcLo, (size_t)128 * DI / 2);
    split_bf16<0><<<64, blk, 0, stream>>>(W_bc, WbcHi, WbcLo, 32, DI, DI);

    // x = hs @ W_in[:DI]^T (split out), z = hs @ W_in[DI:]^T (fp32)
    mfma_gemm<4, 1><<<dim3(DI / 128, NTOK / 128), blk, 0, stream>>>(
        HsHi, HsLo, WinHi, WinLo, nullptr, nullptr, nullptr, XHi, XLo,
        NTOK, DI, DM, 0, 0, DI);
    mfma_gemm<0, 1><<<dim3(DI / 128, NTOK / 128), blk, 0, stream>>>(
        HsHi, HsLo, WinHi + (size_t)DI * DM, WinLo + (size_t)DI * DM,
        nullptr, nullptr, z, nullptr, nullptr, NTOK, DI, DM, 0, 0, DI);

    // xdbl: split-K (8) over K=DI, N padded to 128
    mfma_gemm<0, 1><<<dim3(1, NTOK / 128, 8), blk, 0, stream>>>(
        XHi, XLo, WxHi, WxLo, nullptr, nullptr, Pd, nullptr, nullptr,
        NTOK, 128, DI, 0, 0, 128);
    reduce_xdbl<<<(NTOK * XDBL_N + 255) / 256, blk, 0, stream>>>(Pd, xdbl);

    // delta = softplus(dt_low @ W_dt^T + b_dt)
    split_bf16<0><<<256, blk, 0, stream>>>(xdbl, XdHi, XdLo, NTOK, DTR, XDBL_N);
    mfma_gemm<2, 1><<<dim3(DI / 128, NTOK / 128), blk, 0, stream>>>(
        XdHi, XdLo, WdtHi, WdtLo, nullptr, b_dt, delta, nullptr, nullptr,
        NTOK, DI, DTR, 0, 0, DI);

    bc_init<<<NTOK / 8, 256, 0, stream>>>(xdbl, Btb, Ctb);

    // xWbc = x @ Wbc128^T  (once; cols 0..31 = x @ W_bc^T)
    mfma_gemm<0, 1><<<dim3(1, NTOK / 128), blk, 0, stream>>>(
        XHi, XLo, WbcHi, WbcLo, nullptr, nullptr, xWbc, nullptr, nullptr,
        NTOK, 128, DI, 0, 0, 128);

    // --- fixed-point loop ---
    for (int it = 0; it <= FP_ITERS; ++it) {
        const ushort_t* Ah = (it == 0) ? XHi : AuHi;
        const ushort_t* Al = (it == 0) ? XLo : AuLo;
        // u = (x - y) @ W_mix^T + y   (2-prod iters 0..7; 3-prod final)
        if (it == 0) {
            mfma_gemm<0, 0><<<dim3(DI / 128, NTOK / 128), blk, 0, stream>>>(
                Ah, Al, WmixHi, WmixLo, nullptr, nullptr, ubuf, nullptr, nullptr,
                NTOK, DI, DI, 0, 0, DI);
        } else if (it < FP_ITERS) {
            mfma_gemm<1, 0><<<dim3(DI / 128, NTOK / 128), blk, 0, stream>>>(
                Ah, Al, WmixHi, WmixLo, yA, nullptr, ubuf, nullptr, nullptr,
                NTOK, DI, DI, DI, 0, DI);
        } else {
            mfma_gemm<1, 1><<<dim3(DI / 128, NTOK / 128), blk, 0, stream>>>(
                Ah, Al, WmixHi, WmixLo, yA, nullptr, ubuf, nullptr, nullptr,
                NTOK, DI, DI, DI, 0, DI);
        }
        // P = (x - y) @ Wbc128^T (skinny, split-K); bc = xWbc - P
        if (it > 0) {
            if (it < FP_ITERS)
                mfma_gemm<0, 0><<<dim3(1, NTOK / 128, PKZ), blk, 0, stream>>>(
                    Ah, Al, WbcHi, WbcLo, nullptr, nullptr, Pp, nullptr, nullptr,
                    NTOK, 128, DI, 0, 0, 128);
            else
                mfma_gemm<0, 1><<<dim3(1, NTOK / 128, PKZ), blk, 0, stream>>>(
                    Ah, Al, WbcHi, WbcLo, nullptr, nullptr, Pp, nullptr, nullptr,
                    NTOK, 128, DI, 0, 0, 128);
            bc_make<<<NTOK / 8, blk, 0, stream>>>(xdbl, xWbc, Pp, Btb, Ctb);
        }
        // it == 0: y = 0 -> bc = 0 -> Bt/Ct already bc_init values

        scan_pass1<<<dim3(DI / 256, NCH, B_SZ), blk, 0, stream>>>(
            delta, ubuf, Btb, A_log, Ac, Hend);
        scan_pass2<<<dim3(B_SZ * DI * NST / 256), blk, 0, stream>>>(Ac, Hend);
        scan_pass3<<<dim3(DI / 256, NCH, B_SZ), blk, 0, stream>>>(
            delta, ubuf, Btb, Ctb, A_log, Dp, Ac, yraw);
        ln_update<<<dim3(LSEQ, B_SZ), blk, 0, stream>>>(
            yraw, yA, g_ln, b_ln, XHi, XLo, AuHi, AuLo,
            it == 0 ? 1 : 0, it == FP_ITERS ? 1 : 0);
    }

    // --- epilogue ---
    // g = silu(z + shift1(y) @ W_zy^T) * y   (split into delta buf)
    split_bf16<2><<<8192, blk, 0, stream>>>(yA, XHi, XLo, NTOK, DI, DI);
    split_bf16<0><<<4096, blk, 0, stream>>>(W_zy, WzyHi, WzyLo, DI, DI, DI);
    mfma_gemm<3, 1><<<dim3(DI / 128, NTOK / 128), blk, 0, stream>>>(
        XHi, XLo, WzyHi, WzyLo, z, yA, nullptr, Ghi, Glo,
        NTOK, DI, DI, DI, DI, DI);

    // out = g @ W_out^T
    split_bf16<0><<<2048, blk, 0, stream>>>(W_out, WoutHi, WoutLo, DM, DI, DI);
    mfma_gemm<0, 1><<<dim3(DM / 128, NTOK / 128), blk, 0, stream>>>(
        Ghi, Glo, WoutHi, WoutLo, nullptr, nullptr, out, nullptr, nullptr,
        NTOK, DM, DI, 0, 0, DM);
}

// Round 7
// 2680.322 us; speedup vs baseline: 1.2957x; 1.0066x over previous
//
#include <hip/hip_runtime.h>
#include <math.h>

#define B_SZ   2
#define LSEQ   2048
#define DM     1024
#define DI     2048
#define NST    16
#define DTR    64
#define XDBL_N 96
#define NTOK   (B_SZ * LSEQ)
#define NCH    32
#define CS     64
#define EPSF   1e-5f
#define STEPF  0.99f
#define FP_ITERS 8
#define PKZ    4      // split-K factor for the skinny P-GEMM

typedef __attribute__((ext_vector_type(8))) short bf16x8;
typedef __attribute__((ext_vector_type(4))) float f32x4;
typedef unsigned short ushort_t;

__device__ __forceinline__ ushort_t f2bf(float v) {
    unsigned u = __float_as_uint(v);
    unsigned r = (u + 0x7fffu + ((u >> 16) & 1u)) >> 16;   // RNE
    return (ushort_t)r;
}
__device__ __forceinline__ float bf2f(ushort_t h) {
    return __uint_as_float(((unsigned)h) << 16);
}
__device__ __forceinline__ void split1(float v, ushort_t& h, ushort_t& l) {
    h = f2bf(v);
    l = f2bf(v - bf2f(h));
}
__device__ __forceinline__ void load_lds16(const void* g, void* l) {
    __builtin_amdgcn_global_load_lds(
        (const __attribute__((address_space(1))) unsigned int*)g,
        (__attribute__((address_space(3))) unsigned int*)l, 16, 0, 0);
}

// ---------------------------------------------------------------------------
// Split fp32 -> bf16 hi/lo pair.
// MODE 0: A plain      (lda)
// MODE 2: shift1(A)    (row t reads t-1 within each LSEQ batch)
// ---------------------------------------------------------------------------
template <int MODE>
__global__ __launch_bounds__(256) void split_bf16(
    const float* __restrict__ A,
    ushort_t* __restrict__ Hi, ushort_t* __restrict__ Lo,
    int M, int K, int lda)
{
    int K4 = K >> 2;
    long total = (long)M * K4;
    for (long i = (long)blockIdx.x * 256 + threadIdx.x; i < total;
         i += (long)gridDim.x * 256) {
        int m = (int)(i / K4);
        int k = (int)(i - (long)m * K4) * 4;
        float4 a;
        if (MODE == 2) {
            int t = m & (LSEQ - 1);
            if (t == 0) a = make_float4(0.f, 0.f, 0.f, 0.f);
            else        a = *(const float4*)(A + (size_t)(m - 1) * lda + k);
        } else {
            a = *(const float4*)(A + (size_t)m * lda + k);
        }
        ushort4 hv, lv;
        split1(a.x, hv.x, lv.x);
        split1(a.y, hv.y, lv.y);
        split1(a.z, hv.z, lv.z);
        split1(a.w, hv.w, lv.w);
        *(ushort4*)(Hi + (size_t)m * K + k) = hv;
        *(ushort4*)(Lo + (size_t)m * K + k) = lv;
    }
}

// ---------------------------------------------------------------------------
// Split-bf16 MFMA GEMM, 128x128 tile, BK=32, 256 threads = 4 waves (2x2 of
// 64x64). PROD3: 3 products (hh,hl,lh) vs 2 (hh,hl — Alo NOT staged).
// Split-K via gridDim.z. Grid (N/128, M/128[, splitk]) — keep x-dim a power
// of 2: N=2176 fusion (round 4/5) broke L2 locality (FETCH 172->254 MB).
// EOP: 0 C = acc
//      1 C = acc + E[m][n]                        (ldE)
//      2 C = softplus(acc + E2[n])                (bias vector)
//      3 g = silu(E[m][n]+acc) * E2[m][n]; split -> Chi/Clo
//      4 split(acc) -> Chi/Clo
//      6 xz: gn<DI -> split(acc)->Chi/Clo[gm*ldc+gn]; else C[gm*ldc+gn-DI]
// ---------------------------------------------------------------------------
template <int EOP, int PROD3>
__global__ __launch_bounds__(256) void mfma_gemm(
    const ushort_t* __restrict__ Ahi, const ushort_t* __restrict__ Alo,
    const ushort_t* __restrict__ Whi, const ushort_t* __restrict__ Wlo,
    const float* __restrict__ E, const float* __restrict__ E2,
    float* __restrict__ C, ushort_t* __restrict__ Chi, ushort_t* __restrict__ Clo,
    int M, int N, int K, int ldE, int ldE2, int ldc)
{
    __shared__ __align__(16) short lds[16384];  // 32 KB: Ahi|Alo|Whi|Wlo, each 128x32
    short* sAhi = lds;
    short* sAlo = lds + 4096;
    short* sWhi = lds + 8192;
    short* sWlo = lds + 12288;
    char* ldsc = (char*)lds;

    const int tid = threadIdx.x, lane = tid & 63, w = tid >> 6;
    const int m0 = blockIdx.y * 128, n0 = blockIdx.x * 128;
    const int wm = (w & 1) * 64, wn = (w >> 1) * 64;

    const int ksub = K / gridDim.z;
    const int kbeg = blockIdx.z * ksub;
    if (gridDim.z > 1) C += (size_t)blockIdx.z * M * ldc;

    f32x4 zero4 = {0.f, 0.f, 0.f, 0.f};
    f32x4 acc[4][4];
    #pragma unroll
    for (int mi = 0; mi < 4; ++mi)
        #pragma unroll
        for (int ni = 0; ni < 4; ++ni) acc[mi][ni] = zero4;

    size_t aoff[2], woff[2];
    #pragma unroll
    for (int i = 0; i < 2; ++i) {
        int j = w * 2 + i;
        int row = j * 16 + (lane >> 2);
        int ke = (lane & 3) * 8;
        aoff[i] = (size_t)(m0 + row) * K + kbeg + ke;
        woff[i] = (size_t)(n0 + row) * K + kbeg + ke;
    }
    const int abase = (wm + (lane & 15)) * 32 + (lane >> 4) * 8;
    const int bbase = (wn + (lane & 15)) * 32 + (lane >> 4) * 8;

    for (int k0 = 0; k0 < ksub; k0 += 32) {
        #pragma unroll
        for (int i = 0; i < 2; ++i) {
            int dst = (w * 2 + i) * 1024;
            load_lds16(Ahi + aoff[i], ldsc + dst);
            if (PROD3)
                load_lds16(Alo + aoff[i], ldsc + 8192 + dst);
            load_lds16(Whi + woff[i], ldsc + 16384 + dst);
            load_lds16(Wlo + woff[i], ldsc + 24576 + dst);
            aoff[i] += 32; woff[i] += 32;
        }
        __syncthreads();

        bf16x8 ah[4], al[4], bh[4], bl[4];
        #pragma unroll
        for (int mi = 0; mi < 4; ++mi) {
            ah[mi] = *(const bf16x8*)(sAhi + abase + mi * 512);
            if (PROD3)
                al[mi] = *(const bf16x8*)(sAlo + abase + mi * 512);
        }
        #pragma unroll
        for (int ni = 0; ni < 4; ++ni) {
            bh[ni] = *(const bf16x8*)(sWhi + bbase + ni * 512);
            bl[ni] = *(const bf16x8*)(sWlo + bbase + ni * 512);
        }
        #pragma unroll
        for (int mi = 0; mi < 4; ++mi)
            #pragma unroll
            for (int ni = 0; ni < 4; ++ni) {
                acc[mi][ni] = __builtin_amdgcn_mfma_f32_16x16x32_bf16(ah[mi], bh[ni], acc[mi][ni], 0, 0, 0);
                acc[mi][ni] = __builtin_amdgcn_mfma_f32_16x16x32_bf16(ah[mi], bl[ni], acc[mi][ni], 0, 0, 0);
                if (PROD3)
                    acc[mi][ni] = __builtin_amdgcn_mfma_f32_16x16x32_bf16(al[mi], bh[ni], acc[mi][ni], 0, 0, 0);
            }
        __syncthreads();
    }

    // C/D layout: col = lane&15, row = (lane>>4)*4 + reg
    const int col = lane & 15, rb = (lane >> 4) * 4;
    #pragma unroll
    for (int mi = 0; mi < 4; ++mi) {
        #pragma unroll
        for (int r = 0; r < 4; ++r) {
            int gm = m0 + wm + mi * 16 + rb + r;
            #pragma unroll
            for (int ni = 0; ni < 4; ++ni) {
                int gn = n0 + wn + ni * 16 + col;
                float v = acc[mi][ni][r];
                if (EOP == 0) {
                    C[(size_t)gm * ldc + gn] = v;
                } else if (EOP == 1) {
                    C[(size_t)gm * ldc + gn] = v + E[(size_t)gm * ldE + gn];
                } else if (EOP == 2) {
                    v += E2[gn];
                    v = (v > 20.f) ? v : log1pf(expf(v));
                    C[(size_t)gm * ldc + gn] = v;
                } else if (EOP == 3) {
                    float z2 = E[(size_t)gm * ldE + gn] + v;
                    float s = 1.f / (1.f + __expf(-z2));
                    float g = z2 * s * E2[(size_t)gm * ldE2 + gn];
                    ushort_t h, l;
                    split1(g, h, l);
                    Chi[(size_t)gm * ldc + gn] = h;
                    Clo[(size_t)gm * ldc + gn] = l;
                } else if (EOP == 4) {
                    ushort_t h, l;
                    split1(v, h, l);
                    Chi[(size_t)gm * ldc + gn] = h;
                    Clo[(size_t)gm * ldc + gn] = l;
                } else {  // EOP == 6: xz fused epilogue
                    if (gn < DI) {
                        ushort_t h, l;
                        split1(v, h, l);
                        Chi[(size_t)gm * ldc + gn] = h;
                        Clo[(size_t)gm * ldc + gn] = l;
                    } else {
                        C[(size_t)gm * ldc + (gn - DI)] = v;
                    }
                }
            }
        }
    }
}

// xdbl[m][n] = sum_z Pd[z][m][128+n], n < 96
__global__ __launch_bounds__(256) void reduce_xdbl(
    const float* __restrict__ Pd, float* __restrict__ xdbl)
{
    int idx = blockIdx.x * 256 + threadIdx.x;
    if (idx >= NTOK * XDBL_N) return;
    int m = idx / XDBL_N, n = idx - m * XDBL_N;
    float s = 0.f;
    #pragma unroll
    for (int zz = 0; zz < 8; ++zz)
        s += Pd[(size_t)zz * NTOK * 128 + (size_t)m * 128 + n];
    xdbl[(size_t)m * XDBL_N + n] = s;
}

// ---------------------------------------------------------------------------
// Bt/Ct[t+1] = normalize(B0C0[t+1] + xWbc[t] - sum_z Pp[z][t])
// ---------------------------------------------------------------------------
__global__ __launch_bounds__(256) void bc_make(
    const float* __restrict__ xdbl, const float* __restrict__ xWbc,
    const float* __restrict__ Pp, float* __restrict__ Btb, float* __restrict__ Ctb)
{
    int tok = blockIdx.x * 8 + (threadIdx.x >> 5);
    int j = threadIdx.x & 31;
    int t = tok & (LSEQ - 1);
    if (t == LSEQ - 1) return;
    int tn = tok + 1;
    float p = 0.f;
    #pragma unroll
    for (int zz = 0; zz < PKZ; ++zz)
        p += Pp[(size_t)zz * NTOK * 128 + (size_t)tok * 128 + j];
    float v = xdbl[(size_t)tn * XDBL_N + DTR + j]
            + xWbc[(size_t)tok * 128 + j] - p;
    float sq = v * v;
    #pragma unroll
    for (int off = 8; off >= 1; off >>= 1) sq += __shfl_xor(sq, off, 16);
    float nrm = fmaxf(sqrtf(sq), EPSF);
    float outv = v / nrm;
    if (j < 16) Btb[(size_t)tn * NST + j] = outv;
    else        Ctb[(size_t)tn * NST + (j - 16)] = outv;
}

// ---------------------------------------------------------------------------
// Chunked selective scan.
// ---------------------------------------------------------------------------
__global__ __launch_bounds__(256) void scan_pass1(
    const float* __restrict__ delta, const float* __restrict__ u,
    const float* __restrict__ Bt, const float* __restrict__ Alog,
    float* __restrict__ Ac, float* __restrict__ Hend)
{
    int d = blockIdx.x * 256 + threadIdx.x;
    int c = blockIdx.y, b = blockIdx.z;
    int t0 = c * CS;
    __shared__ float sB[CS][NST];
    for (int i = threadIdx.x; i < CS * NST; i += 256)
        ((float*)sB)[i] = Bt[(size_t)(b * LSEQ + t0) * NST + i];
    __syncthreads();

    float Avals[NST];
    #pragma unroll
    for (int n = 0; n < NST; ++n) Avals[n] = -__expf(Alog[d * NST + n]);
    float h[NST] = {};
    float Pp[NST];
    #pragma unroll
    for (int n = 0; n < NST; ++n) Pp[n] = 1.f;

    const float* dptr = delta + (size_t)(b * LSEQ + t0) * DI + d;
    const float* uptr = u + (size_t)(b * LSEQ + t0) * DI + d;
    for (int tt = 0; tt < CS; ++tt) {
        float dt = dptr[(size_t)tt * DI];
        float ut = uptr[(size_t)tt * DI];
        float wv = dt * ut;
        #pragma unroll
        for (int n = 0; n < NST; ++n) {
            float a = __expf(dt * Avals[n]);
            Pp[n] *= a;
            h[n] = fmaf(a, h[n], wv * sB[tt][n]);
        }
    }
    size_t o = ((size_t)((b * NCH + c) * DI) + d) * NST;
    #pragma unroll
    for (int n = 0; n < NST; ++n) { Ac[o + n] = Pp[n]; Hend[o + n] = h[n]; }
}

__global__ __launch_bounds__(256) void scan_pass2(
    float* __restrict__ Ac, const float* __restrict__ Hend)
{
    int idx = blockIdx.x * 256 + threadIdx.x;
    int b = idx / (DI * NST);
    int dn = idx % (DI * NST);
    float h = 0.f;
    for (int c = 0; c < NCH; ++c) {
        size_t o = (size_t)(b * NCH + c) * DI * NST + dn;
        float a = Ac[o];
        float e = Hend[o];
        Ac[o] = h;               // Hin in place
        h = fmaf(a, h, e);
    }
}

__global__ __launch_bounds__(256) void scan_pass3(
    const float* __restrict__ delta, const float* u,
    const float* __restrict__ Bt, const float* __restrict__ Ct,
    const float* __restrict__ Alog, const float* __restrict__ Dp,
    const float* __restrict__ Hin, float* yraw)  // yraw may alias u
{
    int d = blockIdx.x * 256 + threadIdx.x;
    int c = blockIdx.y, b = blockIdx.z;
    int t0 = c * CS;
    __shared__ float sB[CS][NST];
    __shared__ float sC[CS][NST];
    for (int i = threadIdx.x; i < CS * NST; i += 256) {
        ((float*)sB)[i] = Bt[(size_t)(b * LSEQ + t0) * NST + i];
        ((float*)sC)[i] = Ct[(size_t)(b * LSEQ + t0) * NST + i];
    }
    __syncthreads();

    float Avals[NST];
    #pragma unroll
    for (int n = 0; n < NST; ++n) Avals[n] = -__expf(Alog[d * NST + n]);
    float h[NST];
    size_t o = ((size_t)((b * NCH + c) * DI) + d) * NST;
    #pragma unroll
    for (int n = 0; n < NST; ++n) h[n] = Hin[o + n];
    float Dd = Dp[d];

    const float* dptr = delta + (size_t)(b * LSEQ + t0) * DI + d;
    const float* uptr = u + (size_t)(b * LSEQ + t0) * DI + d;
    float* yptr = yraw + (size_t)(b * LSEQ + t0) * DI + d;
    for (int tt = 0; tt < CS; ++tt) {
        float dt = dptr[(size_t)tt * DI];
        float ut = uptr[(size_t)tt * DI];
        float wv = dt * ut;
        float acc = 0.f;
        #pragma unroll
        for (int n = 0; n < NST; ++n) {
            float a = __expf(dt * Avals[n]);
            h[n] = fmaf(a, h[n], wv * sB[tt][n]);
            acc = fmaf(h[n], sC[tt][n], acc);
        }
        yptr[(size_t)tt * DI] = fmaf(Dd, ut, acc);
    }
}

// ---------------------------------------------------------------------------
// Per-token LN -> fp update (in place) -> split(x - y_next) for next u-GEMM.
// ---------------------------------------------------------------------------
__global__ __launch_bounds__(256) void ln_update(
    const float* __restrict__ yraw, float* __restrict__ ybuf,
    const float* __restrict__ gamma, const float* __restrict__ beta,
    const ushort_t* __restrict__ XHi, const ushort_t* __restrict__ XLo,
    ushort_t* __restrict__ AuHi, ushort_t* __restrict__ AuLo,
    int is_first, int is_final)
{
    int t = blockIdx.x, b = blockIdx.y;
    int tid = threadIdx.x;
    size_t ro = (size_t)(b * LSEQ + t) * DI;
    const float* yr = yraw + ro;
    float* yp = ybuf + ro;

    float s = 0.f, s2 = 0.f;
    float vloc[DI / 256];
    #pragma unroll
    for (int i = 0; i < DI / 256; ++i) {
        float v = yr[tid + i * 256];
        vloc[i] = v; s += v; s2 += v * v;
    }
    #pragma unroll
    for (int off = 32; off >= 1; off >>= 1) {
        s += __shfl_down(s, off, 64);
        s2 += __shfl_down(s2, off, 64);
    }
    __shared__ float rs[4], rs2[4];
    __shared__ float smean, srstd;
    int wid = tid >> 6, lane = tid & 63;
    if (lane == 0) { rs[wid] = s; rs2[wid] = s2; }
    __syncthreads();
    if (tid == 0) {
        float S = rs[0] + rs[1] + rs[2] + rs[3];
        float S2 = rs2[0] + rs2[1] + rs2[2] + rs2[3];
        float m = S / (float)DI;
        float var = S2 / (float)DI - m * m;
        smean = m;
        srstd = rsqrtf(var + EPSF);
    }
    __syncthreads();
    float m = smean, r = srstd;

    #pragma unroll
    for (int i = 0; i < DI / 256; ++i) {
        int idx = tid + i * 256;
        float ln = (vloc[i] - m) * r * gamma[idx] + beta[idx];
        float ypv = is_first ? 0.f : yp[idx];
        float yn = is_final ? ln : fmaf(STEPF, ln - ypv, ypv);
        yp[idx] = yn;
        if (!is_final) {
            float xv = bf2f(XHi[ro + idx]) + bf2f(XLo[ro + idx]);
            ushort_t h, l;
            split1(xv - yn, h, l);
            AuHi[ro + idx] = h;
            AuLo[ro + idx] = l;
        }
    }
}

__global__ __launch_bounds__(256) void bc_init(
    const float* __restrict__ xdbl, float* __restrict__ Btb, float* __restrict__ Ctb)
{
    int tok = blockIdx.x * 8 + (threadIdx.x >> 5);
    int i = threadIdx.x & 31;
    float v = xdbl[(size_t)tok * XDBL_N + DTR + i];
    float sq = v * v;
    #pragma unroll
    for (int off = 8; off >= 1; off >>= 1) sq += __shfl_xor(sq, off, 16);
    float nrm = fmaxf(sqrtf(sq), EPSF);
    float outv = v / nrm;
    if (i < 16) Btb[(size_t)tok * NST + i] = outv;
    else        Ctb[(size_t)tok * NST + (i - 16)] = outv;
}

__global__ __launch_bounds__(256) void fill_zero(float* p, size_t n)
{
    size_t i = (size_t)blockIdx.x * blockDim.x + threadIdx.x;
    size_t stride = (size_t)gridDim.x * blockDim.x;
    for (; i < n; i += stride) p[i] = 0.f;
}

// ---------------------------------------------------------------------------
extern "C" void kernel_launch(void* const* d_in, const int* in_sizes, int n_in,
                              void* d_out, int out_size, void* d_ws, size_t ws_size,
                              hipStream_t stream)
{
    const float* hs    = (const float*)d_in[0];
    const float* W_in  = (const float*)d_in[1];
    const float* W_x   = (const float*)d_in[2];
    const float* W_dt  = (const float*)d_in[3];
    const float* b_dt  = (const float*)d_in[4];
    const float* A_log = (const float*)d_in[5];
    const float* W_bc  = (const float*)d_in[6];
    const float* W_zy  = (const float*)d_in[7];
    const float* W_mix = (const float*)d_in[8];
    const float* Dp    = (const float*)d_in[9];
    const float* g_ln  = (const float*)d_in[10];
    const float* b_ln  = (const float*)d_in[11];
    const float* W_out = (const float*)d_in[12];
    float* out = (float*)d_out;

    char* ws = (char*)d_ws;
    size_t off = 0;
    auto alloc = [&](size_t bytes) {
        void* p = (void*)(ws + off);
        off += (bytes + 255) & ~(size_t)255;
        return p;
    };
    float*    z      = (float*)alloc((size_t)NTOK * DI * 4);       // 32 MB
    ushort_t* XHi    = (ushort_t*)alloc((size_t)NTOK * DI * 2);    // 16 MB (epilogue: shift1(y) hi)
    ushort_t* XLo    = (ushort_t*)alloc((size_t)NTOK * DI * 2);    // 16 MB
    float*    delta  = (float*)alloc((size_t)NTOK * DI * 4);       // 32 MB (epilogue: Ghi|Glo)
    float*    ubuf   = (float*)alloc((size_t)NTOK * DI * 4);       // 32 MB (prologue: hs/Win splits)
    float*    yA     = (float*)alloc((size_t)NTOK * DI * 4);       // 32 MB (prologue: Pd + Xd splits)
    ushort_t* AuHi   = (ushort_t*)alloc((size_t)NTOK * DI * 2);    // 16 MB (prologue: Wx split)
    ushort_t* AuLo   = (ushort_t*)alloc((size_t)NTOK * DI * 2);    // 16 MB (prologue: Wdt split)
    ushort_t* WmixHi = (ushort_t*)alloc((size_t)DI * DI * 2);      // 8 MB (epilogue: Wzy hi)
    ushort_t* WmixLo = (ushort_t*)alloc((size_t)DI * DI * 2);      // 8 MB (epilogue: Wzy lo)
    float*    Ac     = (float*)alloc((size_t)B_SZ * NCH * DI * NST * 4); // 8 MB (epilogue: Wout hi)
    float*    Hend   = (float*)alloc((size_t)B_SZ * NCH * DI * NST * 4); // 8 MB (epilogue: Wout lo)
    float*    xdbl   = (float*)alloc((size_t)NTOK * XDBL_N * 4);   // 1.5 MB
    float*    Btb    = (float*)alloc((size_t)NTOK * NST * 4);
    float*    Ctb    = (float*)alloc((size_t)NTOK * NST * 4);
    float*    Pp     = (float*)alloc((size_t)PKZ * NTOK * 128 * 4);// 8 MB (P partials)
    float*    xWbc   = (float*)alloc((size_t)NTOK * 128 * 4);      // 2 MB
    ushort_t* WbcHi  = (ushort_t*)alloc((size_t)128 * DI * 2);     // 0.5 MB (128 rows: 32 real + 96 zero)
    ushort_t* WbcLo  = (ushort_t*)alloc((size_t)128 * DI * 2);     // 0.5 MB

    // prologue aliases
    ushort_t* HsHi  = (ushort_t*)ubuf;
    ushort_t* HsLo  = HsHi + (size_t)NTOK * DM;
    ushort_t* WinHi = HsLo + (size_t)NTOK * DM;
    ushort_t* WinLo = WinHi + (size_t)(2 * DI) * DM;               // = 32 MB exactly
    float*    Pd    = yA;                                          // 8 x 4096 x 128 = 16 MB
    ushort_t* XdHi  = (ushort_t*)(yA + (size_t)NTOK * DI / 2);     // yA + 16 MB
    ushort_t* XdLo  = XdHi + (size_t)NTOK * DTR;
    ushort_t* WxHi  = AuHi;                                        // 128 x 2048 bf16
    ushort_t* WxLo  = WxHi + (size_t)128 * DI;
    ushort_t* WdtHi = AuLo;                                        // 2048 x 64 bf16
    ushort_t* WdtLo = WdtHi + (size_t)DI * DTR;
    // epilogue aliases
    ushort_t* Ghi   = (ushort_t*)delta;
    ushort_t* Glo   = Ghi + (size_t)NTOK * DI;
    ushort_t* WzyHi = WmixHi;
    ushort_t* WzyLo = WmixLo;
    ushort_t* WoutHi= (ushort_t*)Ac;
    ushort_t* WoutLo= (ushort_t*)Hend;
    float*    yraw  = ubuf;

    dim3 blk(256);

    // --- prologue: splits ---
    split_bf16<0><<<4096, blk, 0, stream>>>(hs, HsHi, HsLo, NTOK, DM, DM);
    split_bf16<0><<<4096, blk, 0, stream>>>(W_in, WinHi, WinLo, 2 * DI, DM, DM);
    fill_zero<<<64, blk, 0, stream>>>((float*)WxHi, (size_t)128 * DI / 2);
    fill_zero<<<64, blk, 0, stream>>>((float*)WxLo, (size_t)128 * DI / 2);
    split_bf16<0><<<512, blk, 0, stream>>>(W_x, WxHi, WxLo, XDBL_N, DI, DI);
    split_bf16<0><<<128, blk, 0, stream>>>(W_dt, WdtHi, WdtLo, DI, DTR, DTR);
    split_bf16<0><<<4096, blk, 0, stream>>>(W_mix, WmixHi, WmixLo, DI, DI, DI);
    fill_zero<<<128, blk, 0, stream>>>((float*)WbcHi, (size_t)128 * DI / 2);
    fill_zero<<<128, blk, 0, stream>>>((float*)WbcLo, (size_t)128 * DI / 2);
    split_bf16<0><<<64, blk, 0, stream>>>(W_bc, WbcHi, WbcLo, 32, DI, DI);

    // xz = hs @ W_in^T in ONE GEMM (grid 32x32 = 1024 blocks, co-resident):
    // cols < DI -> split to XHi/XLo; cols >= DI -> fp32 z
    mfma_gemm<6, 1><<<dim3((2 * DI) / 128, NTOK / 128), blk, 0, stream>>>(
        HsHi, HsLo, WinHi, WinLo, nullptr, nullptr, z, XHi, XLo,
        NTOK, 2 * DI, DM, 0, 0, DI);

    // xdbl: split-K (8) over K=DI, N padded to 128
    mfma_gemm<0, 1><<<dim3(1, NTOK / 128, 8), blk, 0, stream>>>(
        XHi, XLo, WxHi, WxLo, nullptr, nullptr, Pd, nullptr, nullptr,
        NTOK, 128, DI, 0, 0, 128);
    reduce_xdbl<<<(NTOK * XDBL_N + 255) / 256, blk, 0, stream>>>(Pd, xdbl);

    // delta = softplus(dt_low @ W_dt^T + b_dt)
    split_bf16<0><<<256, blk, 0, stream>>>(xdbl, XdHi, XdLo, NTOK, DTR, XDBL_N);
    mfma_gemm<2, 1><<<dim3(DI / 128, NTOK / 128), blk, 0, stream>>>(
        XdHi, XdLo, WdtHi, WdtLo, nullptr, b_dt, delta, nullptr, nullptr,
        NTOK, DI, DTR, 0, 0, DI);

    bc_init<<<NTOK / 8, 256, 0, stream>>>(xdbl, Btb, Ctb);

    // xWbc = x @ Wbc128^T  (once; cols 0..31 = x @ W_bc^T)
    mfma_gemm<0, 1><<<dim3(1, NTOK / 128), blk, 0, stream>>>(
        XHi, XLo, WbcHi, WbcLo, nullptr, nullptr, xWbc, nullptr, nullptr,
        NTOK, 128, DI, 0, 0, 128);

    // --- fixed-point loop ---
    for (int it = 0; it <= FP_ITERS; ++it) {
        const ushort_t* Ah = (it == 0) ? XHi : AuHi;
        const ushort_t* Al = (it == 0) ? XLo : AuLo;
        // u = (x - y) @ W_mix^T + y   (2-prod iters 0..7; 3-prod final)
        if (it == 0) {
            mfma_gemm<0, 0><<<dim3(DI / 128, NTOK / 128), blk, 0, stream>>>(
                Ah, Al, WmixHi, WmixLo, nullptr, nullptr, ubuf, nullptr, nullptr,
                NTOK, DI, DI, 0, 0, DI);
        } else if (it < FP_ITERS) {
            mfma_gemm<1, 0><<<dim3(DI / 128, NTOK / 128), blk, 0, stream>>>(
                Ah, Al, WmixHi, WmixLo, yA, nullptr, ubuf, nullptr, nullptr,
                NTOK, DI, DI, DI, 0, DI);
        } else {
            mfma_gemm<1, 1><<<dim3(DI / 128, NTOK / 128), blk, 0, stream>>>(
                Ah, Al, WmixHi, WmixLo, yA, nullptr, ubuf, nullptr, nullptr,
                NTOK, DI, DI, DI, 0, DI);
        }
        // P = (x - y) @ Wbc128^T (skinny, split-K); bc = xWbc - P
        if (it > 0) {
            if (it < FP_ITERS)
                mfma_gemm<0, 0><<<dim3(1, NTOK / 128, PKZ), blk, 0, stream>>>(
                    Ah, Al, WbcHi, WbcLo, nullptr, nullptr, Pp, nullptr, nullptr,
                    NTOK, 128, DI, 0, 0, 128);
            else
                mfma_gemm<0, 1><<<dim3(1, NTOK / 128, PKZ), blk, 0, stream>>>(
                    Ah, Al, WbcHi, WbcLo, nullptr, nullptr, Pp, nullptr, nullptr,
                    NTOK, 128, DI, 0, 0, 128);
            bc_make<<<NTOK / 8, blk, 0, stream>>>(xdbl, xWbc, Pp, Btb, Ctb);
        }
        // it == 0: y = 0 -> bc = 0 -> Bt/Ct already bc_init values

        scan_pass1<<<dim3(DI / 256, NCH, B_SZ), blk, 0, stream>>>(
            delta, ubuf, Btb, A_log, Ac, Hend);
        scan_pass2<<<dim3(B_SZ * DI * NST / 256), blk, 0, stream>>>(Ac, Hend);
        scan_pass3<<<dim3(DI / 256, NCH, B_SZ), blk, 0, stream>>>(
            delta, ubuf, Btb, Ctb, A_log, Dp, Ac, yraw);
        ln_update<<<dim3(LSEQ, B_SZ), blk, 0, stream>>>(
            yraw, yA, g_ln, b_ln, XHi, XLo, AuHi, AuLo,
            it == 0 ? 1 : 0, it == FP_ITERS ? 1 : 0);
    }

    // --- epilogue ---
    // g = silu(z + shift1(y) @ W_zy^T) * y   (split into delta buf)
    split_bf16<2><<<8192, blk, 0, stream>>>(yA, XHi, XLo, NTOK, DI, DI);
    split_bf16<0><<<4096, blk, 0, stream>>>(W_zy, WzyHi, WzyLo, DI, DI, DI);
    mfma_gemm<3, 1><<<dim3(DI / 128, NTOK / 128), blk, 0, stream>>>(
        XHi, XLo, WzyHi, WzyLo, z, yA, nullptr, Ghi, Glo,
        NTOK, DI, DI, DI, DI, DI);

    // out = g @ W_out^T
    split_bf16<0><<<2048, blk, 0, stream>>>(W_out, WoutHi, WoutLo, DM, DI, DI);
    mfma_gemm<0, 1><<<dim3(DM / 128, NTOK / 128), blk, 0, stream>>>(
        Ghi, Glo, WoutHi, WoutLo, nullptr, nullptr, out, nullptr, nullptr,
        NTOK, DM, DI, 0, 0, DM);
}